// Round 1
// baseline (5786.282 us; speedup 1.0000x reference)
//
#include <hip/hip_runtime.h>
#include <math.h>

#define DD 64
#define EDA 16
#define NF 25   // 9 SH + 16 edge_attr

static __device__ __forceinline__ float silu(float v) {
    return v / (1.0f + __expf(-v));
}

// ---------------- Kernel 1: node MLP  x (N,64) -> x_t (N,64) ----------------
__global__ __launch_bounds__(256) void k_node_mlp(
    const float* __restrict__ x,
    const float* __restrict__ W1, const float* __restrict__ b1,
    const float* __restrict__ W2, const float* __restrict__ b2,
    float* __restrict__ x_t, int n)
{
    __shared__ float sW1[DD*DD];
    __shared__ float sW2[DD*DD];
    __shared__ float sb1[DD], sb2[DD];
    for (int i = threadIdx.x; i < DD*DD; i += 256) { sW1[i] = W1[i]; sW2[i] = W2[i]; }
    if (threadIdx.x < DD) { sb1[threadIdx.x] = b1[threadIdx.x]; sb2[threadIdx.x] = b2[threadIdx.x]; }
    __syncthreads();
    int i = blockIdx.x * 256 + threadIdx.x;
    if (i >= n) return;

    float hid[DD];
    #pragma unroll
    for (int j = 0; j < DD; ++j) hid[j] = sb1[j];

    const float4* xr = (const float4*)(x + (size_t)i * DD);
    #pragma unroll
    for (int k4 = 0; k4 < DD/4; ++k4) {
        float4 v = xr[k4];
        float vals[4] = {v.x, v.y, v.z, v.w};
        #pragma unroll
        for (int u = 0; u < 4; ++u) {
            float xk = vals[u];
            const float4* wr = (const float4*)(sW1 + (4*k4+u)*DD);
            #pragma unroll
            for (int j4 = 0; j4 < DD/4; ++j4) {
                float4 w = wr[j4];
                hid[4*j4+0] = fmaf(xk, w.x, hid[4*j4+0]);
                hid[4*j4+1] = fmaf(xk, w.y, hid[4*j4+1]);
                hid[4*j4+2] = fmaf(xk, w.z, hid[4*j4+2]);
                hid[4*j4+3] = fmaf(xk, w.w, hid[4*j4+3]);
            }
        }
    }
    #pragma unroll
    for (int j = 0; j < DD; ++j) hid[j] = silu(hid[j]);

    float out[DD];
    #pragma unroll
    for (int j = 0; j < DD; ++j) out[j] = sb2[j];
    #pragma unroll 4
    for (int k = 0; k < DD; ++k) {
        float hk = hid[k];
        const float4* wr = (const float4*)(sW2 + k*DD);
        #pragma unroll
        for (int j4 = 0; j4 < DD/4; ++j4) {
            float4 w = wr[j4];
            out[4*j4+0] = fmaf(hk, w.x, out[4*j4+0]);
            out[4*j4+1] = fmaf(hk, w.y, out[4*j4+1]);
            out[4*j4+2] = fmaf(hk, w.z, out[4*j4+2]);
            out[4*j4+3] = fmaf(hk, w.w, out[4*j4+3]);
        }
    }
    float4* orow = (float4*)(x_t + (size_t)i * DD);
    #pragma unroll
    for (int j4 = 0; j4 < DD/4; ++j4) {
        float4 o; o.x = out[4*j4]; o.y = out[4*j4+1]; o.z = out[4*j4+2]; o.w = out[4*j4+3];
        orow[j4] = o;
    }
}

// ------ Kernel 2: fused edge: SH + edge MLP + gather x_t[row] + atomic scatter to s[col] ------
__global__ __launch_bounds__(256) void k_edge(
    const float* __restrict__ pos,
    const float* __restrict__ edge_attr,
    const int* __restrict__ row, const int* __restrict__ col,
    const float* __restrict__ x_t,
    const float* __restrict__ W1, const float* __restrict__ b1,
    const float* __restrict__ W2, const float* __restrict__ b2,
    float* __restrict__ s_acc, float* __restrict__ cnt, int n_e)
{
    __shared__ float sW1[NF*DD];
    __shared__ float sW2[DD*DD];
    __shared__ float sb1[DD], sb2[DD];
    for (int i = threadIdx.x; i < NF*DD; i += 256) sW1[i] = W1[i];
    for (int i = threadIdx.x; i < DD*DD; i += 256) sW2[i] = W2[i];
    if (threadIdx.x < DD) { sb1[threadIdx.x] = b1[threadIdx.x]; sb2[threadIdx.x] = b2[threadIdx.x]; }
    __syncthreads();
    int e = blockIdx.x * 256 + threadIdx.x;
    if (e >= n_e) return;

    int r = row[e], c = col[e];
    float ax = pos[3*r+0] - pos[3*c+0];
    float ay = pos[3*r+1] - pos[3*c+1];
    float az = pos[3*r+2] - pos[3*c+2];
    float len = sqrtf(fmaf(ax,ax, fmaf(ay,ay, az*az)) + 1e-12f);
    float dx = ax/len, dy = ay/len, dz = az/len;
    float n2 = sqrtf(fmaf(dx,dx, fmaf(dy,dy, dz*dz)));
    float inv = 1.0f/(n2 + 1e-10f);
    dx *= inv; dy *= inv; dz *= inv;

    float feat[NF];
    feat[0] = 0.28209479177387814f;
    feat[1] = 0.4886025119029199f*dy;
    feat[2] = 0.4886025119029199f*dz;
    feat[3] = 0.4886025119029199f*dx;
    feat[4] = 1.0925484305920792f*dx*dy;
    feat[5] = 1.0925484305920792f*dy*dz;
    feat[6] = 0.31539156525252005f*(3.0f*dz*dz - 1.0f);
    feat[7] = 1.0925484305920792f*dx*dz;
    feat[8] = 0.5462742152960396f*(dx*dx - dy*dy);
    const float4* ea = (const float4*)(edge_attr + (size_t)e * EDA);
    #pragma unroll
    for (int i4 = 0; i4 < EDA/4; ++i4) {
        float4 v = ea[i4];
        feat[9+4*i4+0] = v.x; feat[9+4*i4+1] = v.y; feat[9+4*i4+2] = v.z; feat[9+4*i4+3] = v.w;
    }

    float hid[DD];
    #pragma unroll
    for (int j = 0; j < DD; ++j) hid[j] = sb1[j];
    #pragma unroll 5
    for (int k = 0; k < NF; ++k) {
        float fk = feat[k];
        const float4* wr = (const float4*)(sW1 + k*DD);
        #pragma unroll
        for (int j4 = 0; j4 < DD/4; ++j4) {
            float4 w = wr[j4];
            hid[4*j4+0] = fmaf(fk, w.x, hid[4*j4+0]);
            hid[4*j4+1] = fmaf(fk, w.y, hid[4*j4+1]);
            hid[4*j4+2] = fmaf(fk, w.z, hid[4*j4+2]);
            hid[4*j4+3] = fmaf(fk, w.w, hid[4*j4+3]);
        }
    }
    #pragma unroll
    for (int j = 0; j < DD; ++j) hid[j] = silu(hid[j]);

    float out[DD];
    #pragma unroll
    for (int j = 0; j < DD; ++j) out[j] = sb2[j];
    #pragma unroll 4
    for (int k = 0; k < DD; ++k) {
        float hk = hid[k];
        const float4* wr = (const float4*)(sW2 + k*DD);
        #pragma unroll
        for (int j4 = 0; j4 < DD/4; ++j4) {
            float4 w = wr[j4];
            out[4*j4+0] = fmaf(hk, w.x, out[4*j4+0]);
            out[4*j4+1] = fmaf(hk, w.y, out[4*j4+1]);
            out[4*j4+2] = fmaf(hk, w.z, out[4*j4+2]);
            out[4*j4+3] = fmaf(hk, w.w, out[4*j4+3]);
        }
    }

    const float4* xtr = (const float4*)(x_t + (size_t)r * DD);
    float* srow = s_acc + (size_t)c * DD;
    #pragma unroll
    for (int j4 = 0; j4 < DD/4; ++j4) {
        float4 xv = xtr[j4];
        unsafeAtomicAdd(srow + 4*j4 + 0, out[4*j4+0]*xv.x);
        unsafeAtomicAdd(srow + 4*j4 + 1, out[4*j4+1]*xv.y);
        unsafeAtomicAdd(srow + 4*j4 + 2, out[4*j4+2]*xv.z);
        unsafeAtomicAdd(srow + 4*j4 + 3, out[4*j4+3]*xv.w);
    }
    unsafeAtomicAdd(cnt + c, 1.0f);
}

// ------ Kernel 3: agg = s/max(cnt,1); h = MLP([agg, x]) -> d_out ------
__global__ __launch_bounds__(256) void k_out_mlp(
    const float* __restrict__ s_acc, const float* __restrict__ cnt,
    const float* __restrict__ x,
    const float* __restrict__ W1, const float* __restrict__ b1,
    const float* __restrict__ W2, const float* __restrict__ b2,
    float* __restrict__ h, int n)
{
    __shared__ float sW1[2*DD*DD];   // 128x64 = 32 KB
    __shared__ float sW2[DD*DD];     // 16 KB
    __shared__ float sb1[DD], sb2[DD];
    for (int i = threadIdx.x; i < 2*DD*DD; i += 256) sW1[i] = W1[i];
    for (int i = threadIdx.x; i < DD*DD; i += 256) sW2[i] = W2[i];
    if (threadIdx.x < DD) { sb1[threadIdx.x] = b1[threadIdx.x]; sb2[threadIdx.x] = b2[threadIdx.x]; }
    __syncthreads();
    int i = blockIdx.x * 256 + threadIdx.x;
    if (i >= n) return;

    float invc = 1.0f / fmaxf(cnt[i], 1.0f);
    float hid[DD];
    #pragma unroll
    for (int j = 0; j < DD; ++j) hid[j] = sb1[j];

    const float4* sr = (const float4*)(s_acc + (size_t)i * DD);
    #pragma unroll
    for (int k4 = 0; k4 < DD/4; ++k4) {
        float4 v = sr[k4];
        float vals[4] = {v.x*invc, v.y*invc, v.z*invc, v.w*invc};
        #pragma unroll
        for (int u = 0; u < 4; ++u) {
            float xk = vals[u];
            const float4* wr = (const float4*)(sW1 + (4*k4+u)*DD);
            #pragma unroll
            for (int j4 = 0; j4 < DD/4; ++j4) {
                float4 w = wr[j4];
                hid[4*j4+0] = fmaf(xk, w.x, hid[4*j4+0]);
                hid[4*j4+1] = fmaf(xk, w.y, hid[4*j4+1]);
                hid[4*j4+2] = fmaf(xk, w.z, hid[4*j4+2]);
                hid[4*j4+3] = fmaf(xk, w.w, hid[4*j4+3]);
            }
        }
    }
    const float4* xr = (const float4*)(x + (size_t)i * DD);
    #pragma unroll
    for (int k4 = 0; k4 < DD/4; ++k4) {
        float4 v = xr[k4];
        float vals[4] = {v.x, v.y, v.z, v.w};
        #pragma unroll
        for (int u = 0; u < 4; ++u) {
            float xk = vals[u];
            const float4* wr = (const float4*)(sW1 + (DD + 4*k4+u)*DD);
            #pragma unroll
            for (int j4 = 0; j4 < DD/4; ++j4) {
                float4 w = wr[j4];
                hid[4*j4+0] = fmaf(xk, w.x, hid[4*j4+0]);
                hid[4*j4+1] = fmaf(xk, w.y, hid[4*j4+1]);
                hid[4*j4+2] = fmaf(xk, w.z, hid[4*j4+2]);
                hid[4*j4+3] = fmaf(xk, w.w, hid[4*j4+3]);
            }
        }
    }
    #pragma unroll
    for (int j = 0; j < DD; ++j) hid[j] = silu(hid[j]);

    float out[DD];
    #pragma unroll
    for (int j = 0; j < DD; ++j) out[j] = sb2[j];
    #pragma unroll 4
    for (int k = 0; k < DD; ++k) {
        float hk = hid[k];
        const float4* wr = (const float4*)(sW2 + k*DD);
        #pragma unroll
        for (int j4 = 0; j4 < DD/4; ++j4) {
            float4 w = wr[j4];
            out[4*j4+0] = fmaf(hk, w.x, out[4*j4+0]);
            out[4*j4+1] = fmaf(hk, w.y, out[4*j4+1]);
            out[4*j4+2] = fmaf(hk, w.z, out[4*j4+2]);
            out[4*j4+3] = fmaf(hk, w.w, out[4*j4+3]);
        }
    }
    float4* orow = (float4*)(h + (size_t)i * DD);
    #pragma unroll
    for (int j4 = 0; j4 < DD/4; ++j4) {
        float4 o; o.x = out[4*j4]; o.y = out[4*j4+1]; o.z = out[4*j4+2]; o.w = out[4*j4+3];
        orow[j4] = o;
    }
}

// ------ Kernel 4: per-feature sum and sumsq of h ------
__global__ __launch_bounds__(256) void k_bn_reduce(
    const float* __restrict__ h, float* __restrict__ sums, int total)
{
    float s = 0.f, q = 0.f;
    int stride = gridDim.x * 256;   // 65536, multiple of 64 -> fixed feature per thread
    for (int i = blockIdx.x*256 + threadIdx.x; i < total; i += stride) {
        float v = h[i];
        s += v; q = fmaf(v, v, q);
    }
    __shared__ float ls[256], lq[256];
    ls[threadIdx.x] = s; lq[threadIdx.x] = q;
    __syncthreads();
    if (threadIdx.x < DD) {
        float as = ls[threadIdx.x] + ls[threadIdx.x+64] + ls[threadIdx.x+128] + ls[threadIdx.x+192];
        float aq = lq[threadIdx.x] + lq[threadIdx.x+64] + lq[threadIdx.x+128] + lq[threadIdx.x+192];
        unsafeAtomicAdd(&sums[threadIdx.x], as);
        unsafeAtomicAdd(&sums[DD+threadIdx.x], aq);
    }
}

// ------ Kernel 5: compute scale/shift ------
__global__ void k_bn_finalize(const float* __restrict__ sums,
                              const float* __restrict__ gamma, const float* __restrict__ beta,
                              float* __restrict__ ss, float inv_n)
{
    int j = threadIdx.x;   // 64 threads
    float m = sums[j] * inv_n;
    float var = sums[DD+j] * inv_n - m*m;
    float sc = gamma[j] * rsqrtf(var + 1e-5f);
    ss[j] = sc;
    ss[DD+j] = beta[j] - m*sc;
}

// ------ Kernel 6: normalize in place ------
__global__ __launch_bounds__(256) void k_bn_norm(
    float* __restrict__ h, const float* __restrict__ ss, int total4)
{
    int g = blockIdx.x*256 + threadIdx.x;
    if (g >= total4) return;
    int f0 = (g*4) & (DD-1);
    float4 v = ((const float4*)h)[g];
    v.x = fmaf(v.x, ss[f0+0], ss[DD+f0+0]);
    v.y = fmaf(v.y, ss[f0+1], ss[DD+f0+1]);
    v.z = fmaf(v.z, ss[f0+2], ss[DD+f0+2]);
    v.w = fmaf(v.w, ss[f0+3], ss[DD+f0+3]);
    ((float4*)h)[g] = v;
}

extern "C" void kernel_launch(void* const* d_in, const int* in_sizes, int n_in,
                              void* d_out, int out_size, void* d_ws, size_t ws_size,
                              hipStream_t stream)
{
    const float* x         = (const float*)d_in[0];
    const float* pos       = (const float*)d_in[1];
    const float* edge_attr = (const float*)d_in[2];
    const int*   row       = (const int*)d_in[3];
    const int*   col       = (const int*)d_in[4];
    const float* nW1 = (const float*)d_in[5];
    const float* nb1 = (const float*)d_in[6];
    const float* nW2 = (const float*)d_in[7];
    const float* nb2 = (const float*)d_in[8];
    const float* eW1 = (const float*)d_in[9];
    const float* eb1 = (const float*)d_in[10];
    const float* eW2 = (const float*)d_in[11];
    const float* eb2 = (const float*)d_in[12];
    const float* oW1 = (const float*)d_in[13];
    const float* ob1 = (const float*)d_in[14];
    const float* oW2 = (const float*)d_in[15];
    const float* ob2 = (const float*)d_in[16];
    const float* gamma = (const float*)d_in[17];
    const float* beta  = (const float*)d_in[18];

    const int N = in_sizes[0] / DD;   // 100000
    const int E = in_sizes[3];        // 1600000

    char* ws = (char*)d_ws;
    float* x_t   = (float*)(ws);                                     // N*64 f32
    float* s_acc = (float*)(ws + (size_t)N*DD*4);                    // N*64 f32
    float* cnt   = (float*)(ws + 2*(size_t)N*DD*4);                  // N f32
    float* sums  = (float*)(ws + 2*(size_t)N*DD*4 + (size_t)N*4);    // 128 f32
    float* ssbuf = sums + 2*DD;                                      // 128 f32
    float* hout  = (float*)d_out;

    // zero accumulators (s_acc, cnt, sums) in one shot — they are contiguous
    hipMemsetAsync(s_acc, 0, (size_t)N*DD*4 + (size_t)N*4 + 2*DD*4, stream);

    k_node_mlp<<<(N+255)/256, 256, 0, stream>>>(x, nW1, nb1, nW2, nb2, x_t, N);
    k_edge<<<(E+255)/256, 256, 0, stream>>>(pos, edge_attr, row, col, x_t,
                                            eW1, eb1, eW2, eb2, s_acc, cnt, E);
    k_out_mlp<<<(N+255)/256, 256, 0, stream>>>(s_acc, cnt, x, oW1, ob1, oW2, ob2, hout, N);
    k_bn_reduce<<<256, 256, 0, stream>>>(hout, sums, N*DD);
    k_bn_finalize<<<1, 64, 0, stream>>>(sums, gamma, beta, ssbuf, 1.0f/(float)N);
    k_bn_norm<<<(N*DD/4 + 255)/256, 256, 0, stream>>>(hout, ssbuf, N*DD/4);
}

// Round 2
// 1184.729 us; speedup vs baseline: 4.8841x; 4.8841x over previous
//
#include <hip/hip_runtime.h>
#include <math.h>

#define DD 64
#define EDA 16
#define NF 25   // 9 SH + 16 edge_attr

typedef unsigned int u32;

static __device__ __forceinline__ float silu(float v) {
    return v / (1.0f + __expf(-v));
}

static __device__ __forceinline__ unsigned short f2bf(float f) {
    unsigned u = __float_as_uint(f);
    unsigned r = u + 0x7FFFu + ((u >> 16) & 1u);   // RNE
    return (unsigned short)(r >> 16);
}
static __device__ __forceinline__ unsigned pk2(float a, float b) {
    return (unsigned)f2bf(a) | ((unsigned)f2bf(b) << 16);
}
static __device__ __forceinline__ float bf2f(unsigned short u) {
    return __uint_as_float(((unsigned)u) << 16);
}

// ---------------- Kernel: node MLP  x (N,64) -> x_t (N,64) ----------------
__global__ __launch_bounds__(256) void k_node_mlp(
    const float* __restrict__ x,
    const float* __restrict__ W1, const float* __restrict__ b1,
    const float* __restrict__ W2, const float* __restrict__ b2,
    float* __restrict__ x_t, int n)
{
    __shared__ float sW1[DD*DD];
    __shared__ float sW2[DD*DD];
    __shared__ float sb1[DD], sb2[DD];
    for (int i = threadIdx.x; i < DD*DD; i += 256) { sW1[i] = W1[i]; sW2[i] = W2[i]; }
    if (threadIdx.x < DD) { sb1[threadIdx.x] = b1[threadIdx.x]; sb2[threadIdx.x] = b2[threadIdx.x]; }
    __syncthreads();
    int i = blockIdx.x * 256 + threadIdx.x;
    if (i >= n) return;

    float hid[DD];
    #pragma unroll
    for (int j = 0; j < DD; ++j) hid[j] = sb1[j];

    const float4* xr = (const float4*)(x + (size_t)i * DD);
    #pragma unroll
    for (int k4 = 0; k4 < DD/4; ++k4) {
        float4 v = xr[k4];
        float vals[4] = {v.x, v.y, v.z, v.w};
        #pragma unroll
        for (int u = 0; u < 4; ++u) {
            float xk = vals[u];
            const float4* wr = (const float4*)(sW1 + (4*k4+u)*DD);
            #pragma unroll
            for (int j4 = 0; j4 < DD/4; ++j4) {
                float4 w = wr[j4];
                hid[4*j4+0] = fmaf(xk, w.x, hid[4*j4+0]);
                hid[4*j4+1] = fmaf(xk, w.y, hid[4*j4+1]);
                hid[4*j4+2] = fmaf(xk, w.z, hid[4*j4+2]);
                hid[4*j4+3] = fmaf(xk, w.w, hid[4*j4+3]);
            }
        }
    }
    #pragma unroll
    for (int j = 0; j < DD; ++j) hid[j] = silu(hid[j]);

    float out[DD];
    #pragma unroll
    for (int j = 0; j < DD; ++j) out[j] = sb2[j];
    #pragma unroll 4
    for (int k = 0; k < DD; ++k) {
        float hk = hid[k];
        const float4* wr = (const float4*)(sW2 + k*DD);
        #pragma unroll
        for (int j4 = 0; j4 < DD/4; ++j4) {
            float4 w = wr[j4];
            out[4*j4+0] = fmaf(hk, w.x, out[4*j4+0]);
            out[4*j4+1] = fmaf(hk, w.y, out[4*j4+1]);
            out[4*j4+2] = fmaf(hk, w.z, out[4*j4+2]);
            out[4*j4+3] = fmaf(hk, w.w, out[4*j4+3]);
        }
    }
    float4* orow = (float4*)(x_t + (size_t)i * DD);
    #pragma unroll
    for (int j4 = 0; j4 < DD/4; ++j4) {
        float4 o; o.x = out[4*j4]; o.y = out[4*j4+1]; o.z = out[4*j4+2]; o.w = out[4*j4+3];
        orow[j4] = o;
    }
}

// ---------------- Sort-path kernels ----------------

// histogram of col
__global__ __launch_bounds__(256) void k_hist(
    const int* __restrict__ col, u32* __restrict__ cnt, int n_e)
{
    int g = blockIdx.x * 256 + threadIdx.x;
    int base = g * 4;
    if (base + 3 < n_e) {
        int4 c = ((const int4*)col)[g];
        atomicAdd(&cnt[c.x], 1u);
        atomicAdd(&cnt[c.y], 1u);
        atomicAdd(&cnt[c.z], 1u);
        atomicAdd(&cnt[c.w], 1u);
    } else {
        for (int e = base; e < n_e; ++e) atomicAdd(&cnt[col[e]], 1u);
    }
}

// per-block sums of cnt
__global__ __launch_bounds__(256) void k_scan1(
    const u32* __restrict__ cnt, u32* __restrict__ bsum, int n)
{
    __shared__ u32 s[256];
    int i = blockIdx.x * 256 + threadIdx.x;
    s[threadIdx.x] = (i < n) ? cnt[i] : 0u;
    __syncthreads();
    for (int o = 128; o > 0; o >>= 1) {
        if (threadIdx.x < o) s[threadIdx.x] += s[threadIdx.x + o];
        __syncthreads();
    }
    if (threadIdx.x == 0) bsum[blockIdx.x] = s[0];
}

// exclusive scan of block sums (single block, 512 threads, nb <= 512)
__global__ __launch_bounds__(512) void k_scan2(
    const u32* __restrict__ bsum, u32* __restrict__ boff, int nb)
{
    __shared__ u32 s[512];
    int t = threadIdx.x;
    u32 v = (t < nb) ? bsum[t] : 0u;
    s[t] = v;
    __syncthreads();
    for (int o = 1; o < 512; o <<= 1) {
        u32 a = (t >= o) ? s[t - o] : 0u;
        __syncthreads();
        s[t] += a;
        __syncthreads();
    }
    if (t < nb) boff[t] = s[t] - v;   // exclusive
}

// per-element exclusive scan + block offset -> offs, wp
__global__ __launch_bounds__(256) void k_scan3(
    const u32* __restrict__ cnt, const u32* __restrict__ boff,
    u32* __restrict__ offs, u32* __restrict__ wp, int n)
{
    __shared__ u32 s[256];
    int t = threadIdx.x;
    int i = blockIdx.x * 256 + t;
    u32 v = (i < n) ? cnt[i] : 0u;
    s[t] = v;
    __syncthreads();
    for (int o = 1; o < 256; o <<= 1) {
        u32 a = (t >= o) ? s[t - o] : 0u;
        __syncthreads();
        s[t] += a;
        __syncthreads();
    }
    u32 off = boff[blockIdx.x] + s[t] - v;
    if (i < n) { offs[i] = off; wp[i] = off; }
}

// fused edge: SH + edge MLP + gather x_t[row] + bf16 scatter into sorted slot
__global__ __launch_bounds__(256) void k_edge_scatter(
    const float* __restrict__ pos,
    const float* __restrict__ edge_attr,
    const int* __restrict__ row, const int* __restrict__ col,
    const float* __restrict__ x_t,
    const float* __restrict__ W1, const float* __restrict__ b1,
    const float* __restrict__ W2, const float* __restrict__ b2,
    u32* __restrict__ wp, unsigned short* __restrict__ msg, int n_e)
{
    __shared__ float sW1[NF*DD];
    __shared__ float sW2[DD*DD];
    __shared__ float sb1[DD], sb2[DD];
    for (int i = threadIdx.x; i < NF*DD; i += 256) sW1[i] = W1[i];
    for (int i = threadIdx.x; i < DD*DD; i += 256) sW2[i] = W2[i];
    if (threadIdx.x < DD) { sb1[threadIdx.x] = b1[threadIdx.x]; sb2[threadIdx.x] = b2[threadIdx.x]; }
    __syncthreads();
    int e = blockIdx.x * 256 + threadIdx.x;
    if (e >= n_e) return;

    int r = row[e], c = col[e];
    u32 p_ = atomicAdd(&wp[c], 1u);   // issue early; latency hides under MLP

    float ax = pos[3*r+0] - pos[3*c+0];
    float ay = pos[3*r+1] - pos[3*c+1];
    float az = pos[3*r+2] - pos[3*c+2];
    float len = sqrtf(fmaf(ax,ax, fmaf(ay,ay, az*az)) + 1e-12f);
    float dx = ax/len, dy = ay/len, dz = az/len;
    float n2 = sqrtf(fmaf(dx,dx, fmaf(dy,dy, dz*dz)));
    float inv = 1.0f/(n2 + 1e-10f);
    dx *= inv; dy *= inv; dz *= inv;

    float feat[NF];
    feat[0] = 0.28209479177387814f;
    feat[1] = 0.4886025119029199f*dy;
    feat[2] = 0.4886025119029199f*dz;
    feat[3] = 0.4886025119029199f*dx;
    feat[4] = 1.0925484305920792f*dx*dy;
    feat[5] = 1.0925484305920792f*dy*dz;
    feat[6] = 0.31539156525252005f*(3.0f*dz*dz - 1.0f);
    feat[7] = 1.0925484305920792f*dx*dz;
    feat[8] = 0.5462742152960396f*(dx*dx - dy*dy);
    const float4* ea = (const float4*)(edge_attr + (size_t)e * EDA);
    #pragma unroll
    for (int i4 = 0; i4 < EDA/4; ++i4) {
        float4 v = ea[i4];
        feat[9+4*i4+0] = v.x; feat[9+4*i4+1] = v.y; feat[9+4*i4+2] = v.z; feat[9+4*i4+3] = v.w;
    }

    float hid[DD];
    #pragma unroll
    for (int j = 0; j < DD; ++j) hid[j] = sb1[j];
    #pragma unroll 5
    for (int k = 0; k < NF; ++k) {
        float fk = feat[k];
        const float4* wr = (const float4*)(sW1 + k*DD);
        #pragma unroll
        for (int j4 = 0; j4 < DD/4; ++j4) {
            float4 w = wr[j4];
            hid[4*j4+0] = fmaf(fk, w.x, hid[4*j4+0]);
            hid[4*j4+1] = fmaf(fk, w.y, hid[4*j4+1]);
            hid[4*j4+2] = fmaf(fk, w.z, hid[4*j4+2]);
            hid[4*j4+3] = fmaf(fk, w.w, hid[4*j4+3]);
        }
    }
    #pragma unroll
    for (int j = 0; j < DD; ++j) hid[j] = silu(hid[j]);

    float out[DD];
    #pragma unroll
    for (int j = 0; j < DD; ++j) out[j] = sb2[j];
    #pragma unroll 4
    for (int k = 0; k < DD; ++k) {
        float hk = hid[k];
        const float4* wr = (const float4*)(sW2 + k*DD);
        #pragma unroll
        for (int j4 = 0; j4 < DD/4; ++j4) {
            float4 w = wr[j4];
            out[4*j4+0] = fmaf(hk, w.x, out[4*j4+0]);
            out[4*j4+1] = fmaf(hk, w.y, out[4*j4+1]);
            out[4*j4+2] = fmaf(hk, w.z, out[4*j4+2]);
            out[4*j4+3] = fmaf(hk, w.w, out[4*j4+3]);
        }
    }

    const float4* xtr = (const float4*)(x_t + (size_t)r * DD);
    unsigned short* mrow = msg + (size_t)p_ * DD;
    #pragma unroll
    for (int q = 0; q < 8; ++q) {
        float4 xa = xtr[2*q], xb = xtr[2*q+1];
        uint4 pk;
        pk.x = pk2(out[8*q+0]*xa.x, out[8*q+1]*xa.y);
        pk.y = pk2(out[8*q+2]*xa.z, out[8*q+3]*xa.w);
        pk.z = pk2(out[8*q+4]*xb.x, out[8*q+5]*xb.y);
        pk.w = pk2(out[8*q+6]*xb.z, out[8*q+7]*xb.w);
        ((uint4*)mrow)[q] = pk;
    }
}

// wave-per-node segment mean: agg[n][f] = sum(msg[seg]) / max(cnt,1)
__global__ __launch_bounds__(256) void k_agg(
    const unsigned short* __restrict__ msg,
    const u32* __restrict__ offs, const u32* __restrict__ cnt,
    float* __restrict__ agg, int n)
{
    int node = (blockIdx.x * 256 + threadIdx.x) >> 6;
    int lane = threadIdx.x & 63;
    if (node >= n) return;
    u32 off = offs[node], c = cnt[node];
    const unsigned short* p = msg + (size_t)off * DD + lane;
    float a0 = 0.f, a1 = 0.f, a2 = 0.f, a3 = 0.f;
    u32 i = 0;
    for (; i + 4 <= c; i += 4) {
        a0 += bf2f(p[0]);
        a1 += bf2f(p[DD]);
        a2 += bf2f(p[2*DD]);
        a3 += bf2f(p[3*DD]);
        p += 4*DD;
    }
    for (; i < c; ++i) { a0 += bf2f(p[0]); p += DD; }
    float acc = (a0 + a1) + (a2 + a3);
    agg[(size_t)node * DD + lane] = acc / fmaxf((float)c, 1.0f);
}

// ---------------- Legacy atomic path (fallback if ws too small) ----------------
__global__ __launch_bounds__(256) void k_edge_atomic(
    const float* __restrict__ pos,
    const float* __restrict__ edge_attr,
    const int* __restrict__ row, const int* __restrict__ col,
    const float* __restrict__ x_t,
    const float* __restrict__ W1, const float* __restrict__ b1,
    const float* __restrict__ W2, const float* __restrict__ b2,
    float* __restrict__ s_acc, float* __restrict__ cntf, int n_e)
{
    __shared__ float sW1[NF*DD];
    __shared__ float sW2[DD*DD];
    __shared__ float sb1[DD], sb2[DD];
    for (int i = threadIdx.x; i < NF*DD; i += 256) sW1[i] = W1[i];
    for (int i = threadIdx.x; i < DD*DD; i += 256) sW2[i] = W2[i];
    if (threadIdx.x < DD) { sb1[threadIdx.x] = b1[threadIdx.x]; sb2[threadIdx.x] = b2[threadIdx.x]; }
    __syncthreads();
    int e = blockIdx.x * 256 + threadIdx.x;
    if (e >= n_e) return;

    int r = row[e], c = col[e];
    float ax = pos[3*r+0] - pos[3*c+0];
    float ay = pos[3*r+1] - pos[3*c+1];
    float az = pos[3*r+2] - pos[3*c+2];
    float len = sqrtf(fmaf(ax,ax, fmaf(ay,ay, az*az)) + 1e-12f);
    float dx = ax/len, dy = ay/len, dz = az/len;
    float n2 = sqrtf(fmaf(dx,dx, fmaf(dy,dy, dz*dz)));
    float inv = 1.0f/(n2 + 1e-10f);
    dx *= inv; dy *= inv; dz *= inv;

    float feat[NF];
    feat[0] = 0.28209479177387814f;
    feat[1] = 0.4886025119029199f*dy;
    feat[2] = 0.4886025119029199f*dz;
    feat[3] = 0.4886025119029199f*dx;
    feat[4] = 1.0925484305920792f*dx*dy;
    feat[5] = 1.0925484305920792f*dy*dz;
    feat[6] = 0.31539156525252005f*(3.0f*dz*dz - 1.0f);
    feat[7] = 1.0925484305920792f*dx*dz;
    feat[8] = 0.5462742152960396f*(dx*dx - dy*dy);
    const float4* ea = (const float4*)(edge_attr + (size_t)e * EDA);
    #pragma unroll
    for (int i4 = 0; i4 < EDA/4; ++i4) {
        float4 v = ea[i4];
        feat[9+4*i4+0] = v.x; feat[9+4*i4+1] = v.y; feat[9+4*i4+2] = v.z; feat[9+4*i4+3] = v.w;
    }

    float hid[DD];
    #pragma unroll
    for (int j = 0; j < DD; ++j) hid[j] = sb1[j];
    #pragma unroll 5
    for (int k = 0; k < NF; ++k) {
        float fk = feat[k];
        const float4* wr = (const float4*)(sW1 + k*DD);
        #pragma unroll
        for (int j4 = 0; j4 < DD/4; ++j4) {
            float4 w = wr[j4];
            hid[4*j4+0] = fmaf(fk, w.x, hid[4*j4+0]);
            hid[4*j4+1] = fmaf(fk, w.y, hid[4*j4+1]);
            hid[4*j4+2] = fmaf(fk, w.z, hid[4*j4+2]);
            hid[4*j4+3] = fmaf(fk, w.w, hid[4*j4+3]);
        }
    }
    #pragma unroll
    for (int j = 0; j < DD; ++j) hid[j] = silu(hid[j]);

    float out[DD];
    #pragma unroll
    for (int j = 0; j < DD; ++j) out[j] = sb2[j];
    #pragma unroll 4
    for (int k = 0; k < DD; ++k) {
        float hk = hid[k];
        const float4* wr = (const float4*)(sW2 + k*DD);
        #pragma unroll
        for (int j4 = 0; j4 < DD/4; ++j4) {
            float4 w = wr[j4];
            out[4*j4+0] = fmaf(hk, w.x, out[4*j4+0]);
            out[4*j4+1] = fmaf(hk, w.y, out[4*j4+1]);
            out[4*j4+2] = fmaf(hk, w.z, out[4*j4+2]);
            out[4*j4+3] = fmaf(hk, w.w, out[4*j4+3]);
        }
    }

    const float4* xtr = (const float4*)(x_t + (size_t)r * DD);
    float* srow = s_acc + (size_t)c * DD;
    #pragma unroll
    for (int j4 = 0; j4 < DD/4; ++j4) {
        float4 xv = xtr[j4];
        unsafeAtomicAdd(srow + 4*j4 + 0, out[4*j4+0]*xv.x);
        unsafeAtomicAdd(srow + 4*j4 + 1, out[4*j4+1]*xv.y);
        unsafeAtomicAdd(srow + 4*j4 + 2, out[4*j4+2]*xv.z);
        unsafeAtomicAdd(srow + 4*j4 + 3, out[4*j4+3]*xv.w);
    }
    unsafeAtomicAdd(cntf + c, 1.0f);
}

// ------ out MLP: h = MLP([in0 (maybe /cnt), x]) -> d_out ------
__global__ __launch_bounds__(256) void k_out_mlp(
    const float* __restrict__ in0, const float* __restrict__ cntf,
    const float* __restrict__ x,
    const float* __restrict__ W1, const float* __restrict__ b1,
    const float* __restrict__ W2, const float* __restrict__ b2,
    float* __restrict__ h, int n)
{
    __shared__ float sW1[2*DD*DD];
    __shared__ float sW2[DD*DD];
    __shared__ float sb1[DD], sb2[DD];
    for (int i = threadIdx.x; i < 2*DD*DD; i += 256) sW1[i] = W1[i];
    for (int i = threadIdx.x; i < DD*DD; i += 256) sW2[i] = W2[i];
    if (threadIdx.x < DD) { sb1[threadIdx.x] = b1[threadIdx.x]; sb2[threadIdx.x] = b2[threadIdx.x]; }
    __syncthreads();
    int i = blockIdx.x * 256 + threadIdx.x;
    if (i >= n) return;

    float invc = cntf ? 1.0f / fmaxf(cntf[i], 1.0f) : 1.0f;
    float hid[DD];
    #pragma unroll
    for (int j = 0; j < DD; ++j) hid[j] = sb1[j];

    const float4* sr = (const float4*)(in0 + (size_t)i * DD);
    #pragma unroll
    for (int k4 = 0; k4 < DD/4; ++k4) {
        float4 v = sr[k4];
        float vals[4] = {v.x*invc, v.y*invc, v.z*invc, v.w*invc};
        #pragma unroll
        for (int u = 0; u < 4; ++u) {
            float xk = vals[u];
            const float4* wr = (const float4*)(sW1 + (4*k4+u)*DD);
            #pragma unroll
            for (int j4 = 0; j4 < DD/4; ++j4) {
                float4 w = wr[j4];
                hid[4*j4+0] = fmaf(xk, w.x, hid[4*j4+0]);
                hid[4*j4+1] = fmaf(xk, w.y, hid[4*j4+1]);
                hid[4*j4+2] = fmaf(xk, w.z, hid[4*j4+2]);
                hid[4*j4+3] = fmaf(xk, w.w, hid[4*j4+3]);
            }
        }
    }
    const float4* xr = (const float4*)(x + (size_t)i * DD);
    #pragma unroll
    for (int k4 = 0; k4 < DD/4; ++k4) {
        float4 v = xr[k4];
        float vals[4] = {v.x, v.y, v.z, v.w};
        #pragma unroll
        for (int u = 0; u < 4; ++u) {
            float xk = vals[u];
            const float4* wr = (const float4*)(sW1 + (DD + 4*k4+u)*DD);
            #pragma unroll
            for (int j4 = 0; j4 < DD/4; ++j4) {
                float4 w = wr[j4];
                hid[4*j4+0] = fmaf(xk, w.x, hid[4*j4+0]);
                hid[4*j4+1] = fmaf(xk, w.y, hid[4*j4+1]);
                hid[4*j4+2] = fmaf(xk, w.z, hid[4*j4+2]);
                hid[4*j4+3] = fmaf(xk, w.w, hid[4*j4+3]);
            }
        }
    }
    #pragma unroll
    for (int j = 0; j < DD; ++j) hid[j] = silu(hid[j]);

    float out[DD];
    #pragma unroll
    for (int j = 0; j < DD; ++j) out[j] = sb2[j];
    #pragma unroll 4
    for (int k = 0; k < DD; ++k) {
        float hk = hid[k];
        const float4* wr = (const float4*)(sW2 + k*DD);
        #pragma unroll
        for (int j4 = 0; j4 < DD/4; ++j4) {
            float4 w = wr[j4];
            out[4*j4+0] = fmaf(hk, w.x, out[4*j4+0]);
            out[4*j4+1] = fmaf(hk, w.y, out[4*j4+1]);
            out[4*j4+2] = fmaf(hk, w.z, out[4*j4+2]);
            out[4*j4+3] = fmaf(hk, w.w, out[4*j4+3]);
        }
    }
    float4* orow = (float4*)(h + (size_t)i * DD);
    #pragma unroll
    for (int j4 = 0; j4 < DD/4; ++j4) {
        float4 o; o.x = out[4*j4]; o.y = out[4*j4+1]; o.z = out[4*j4+2]; o.w = out[4*j4+3];
        orow[j4] = o;
    }
}

// ------ BN kernels ------
__global__ __launch_bounds__(256) void k_bn_reduce(
    const float* __restrict__ h, float* __restrict__ sums, int total)
{
    float s = 0.f, q = 0.f;
    int stride = gridDim.x * 256;
    for (int i = blockIdx.x*256 + threadIdx.x; i < total; i += stride) {
        float v = h[i];
        s += v; q = fmaf(v, v, q);
    }
    __shared__ float ls[256], lq[256];
    ls[threadIdx.x] = s; lq[threadIdx.x] = q;
    __syncthreads();
    if (threadIdx.x < DD) {
        float as = ls[threadIdx.x] + ls[threadIdx.x+64] + ls[threadIdx.x+128] + ls[threadIdx.x+192];
        float aq = lq[threadIdx.x] + lq[threadIdx.x+64] + lq[threadIdx.x+128] + lq[threadIdx.x+192];
        unsafeAtomicAdd(&sums[threadIdx.x], as);
        unsafeAtomicAdd(&sums[DD+threadIdx.x], aq);
    }
}

__global__ void k_bn_finalize(const float* __restrict__ sums,
                              const float* __restrict__ gamma, const float* __restrict__ beta,
                              float* __restrict__ ss, float inv_n)
{
    int j = threadIdx.x;   // 64 threads
    float m = sums[j] * inv_n;
    float var = sums[DD+j] * inv_n - m*m;
    float sc = gamma[j] * rsqrtf(var + 1e-5f);
    ss[j] = sc;
    ss[DD+j] = beta[j] - m*sc;
}

__global__ __launch_bounds__(256) void k_bn_norm(
    float* __restrict__ h, const float* __restrict__ ss, int total4)
{
    int g = blockIdx.x*256 + threadIdx.x;
    if (g >= total4) return;
    int f0 = (g*4) & (DD-1);
    float4 v = ((const float4*)h)[g];
    v.x = fmaf(v.x, ss[f0+0], ss[DD+f0+0]);
    v.y = fmaf(v.y, ss[f0+1], ss[DD+f0+1]);
    v.z = fmaf(v.z, ss[f0+2], ss[DD+f0+2]);
    v.w = fmaf(v.w, ss[f0+3], ss[DD+f0+3]);
    ((float4*)h)[g] = v;
}

extern "C" void kernel_launch(void* const* d_in, const int* in_sizes, int n_in,
                              void* d_out, int out_size, void* d_ws, size_t ws_size,
                              hipStream_t stream)
{
    const float* x         = (const float*)d_in[0];
    const float* pos       = (const float*)d_in[1];
    const float* edge_attr = (const float*)d_in[2];
    const int*   row       = (const int*)d_in[3];
    const int*   col       = (const int*)d_in[4];
    const float* nW1 = (const float*)d_in[5];
    const float* nb1 = (const float*)d_in[6];
    const float* nW2 = (const float*)d_in[7];
    const float* nb2 = (const float*)d_in[8];
    const float* eW1 = (const float*)d_in[9];
    const float* eb1 = (const float*)d_in[10];
    const float* eW2 = (const float*)d_in[11];
    const float* eb2 = (const float*)d_in[12];
    const float* oW1 = (const float*)d_in[13];
    const float* ob1 = (const float*)d_in[14];
    const float* oW2 = (const float*)d_in[15];
    const float* ob2 = (const float*)d_in[16];
    const float* gamma = (const float*)d_in[17];
    const float* beta  = (const float*)d_in[18];

    const int N = in_sizes[0] / DD;   // 100000
    const int E = in_sizes[3];        // 1600000
    const int NB = (N + 255) / 256;   // 391

    float* hout = (float*)d_out;
    char* ws = (char*)d_ws;

    // ---- sort-path workspace layout ----
    size_t o_xt   = 0;
    size_t o_msg  = o_xt  + (size_t)N*DD*4;          // bf16 msg: E*64*2
    size_t o_agg  = o_msg + (size_t)E*DD*2;
    size_t o_cnt  = o_agg + (size_t)N*DD*4;
    size_t o_sums = o_cnt + (size_t)N*4;             // 128 f32 (memset with cnt)
    size_t o_ss   = o_sums + 128*4;                  // 128 f32
    size_t o_offs = o_ss  + 128*4;
    size_t o_wp   = o_offs + (size_t)N*4;
    size_t o_bsum = o_wp  + (size_t)N*4;
    size_t o_boff = o_bsum + (size_t)NB*4;
    size_t needA  = o_boff + (size_t)NB*4;

    if (ws_size >= needA) {
        float* x_t  = (float*)(ws + o_xt);
        unsigned short* msg = (unsigned short*)(ws + o_msg);
        float* agg  = (float*)(ws + o_agg);
        u32*   cnt  = (u32*)(ws + o_cnt);
        float* sums = (float*)(ws + o_sums);
        float* ssb  = (float*)(ws + o_ss);
        u32*   offs = (u32*)(ws + o_offs);
        u32*   wp   = (u32*)(ws + o_wp);
        u32*   bsum = (u32*)(ws + o_bsum);
        u32*   boff = (u32*)(ws + o_boff);

        hipMemsetAsync(cnt, 0, (size_t)N*4 + 128*4, stream);   // cnt + sums

        k_hist <<<(E/4 + 255)/256, 256, 0, stream>>>(col, cnt, E);
        k_scan1<<<NB, 256, 0, stream>>>(cnt, bsum, N);
        k_scan2<<<1, 512, 0, stream>>>(bsum, boff, NB);
        k_scan3<<<NB, 256, 0, stream>>>(cnt, boff, offs, wp, N);
        k_node_mlp<<<NB, 256, 0, stream>>>(x, nW1, nb1, nW2, nb2, x_t, N);
        k_edge_scatter<<<(E + 255)/256, 256, 0, stream>>>(pos, edge_attr, row, col, x_t,
                                                          eW1, eb1, eW2, eb2, wp, msg, E);
        k_agg<<<(N*64 + 255)/256, 256, 0, stream>>>(msg, offs, cnt, agg, N);
        k_out_mlp<<<NB, 256, 0, stream>>>(agg, nullptr, x, oW1, ob1, oW2, ob2, hout, N);
        k_bn_reduce<<<256, 256, 0, stream>>>(hout, sums, N*DD);
        k_bn_finalize<<<1, 64, 0, stream>>>(sums, gamma, beta, ssb, 1.0f/(float)N);
        k_bn_norm<<<(N*DD/4 + 255)/256, 256, 0, stream>>>(hout, ssb, N*DD/4);
    } else {
        // ---- fallback: R1 atomic path (needs ~52 MB) ----
        float* x_t   = (float*)(ws);
        float* s_acc = (float*)(ws + (size_t)N*DD*4);
        float* cntf  = (float*)(ws + 2*(size_t)N*DD*4);
        float* sums  = (float*)(ws + 2*(size_t)N*DD*4 + (size_t)N*4);
        float* ssb   = sums + 2*DD;

        hipMemsetAsync(s_acc, 0, (size_t)N*DD*4 + (size_t)N*4 + 2*DD*4, stream);

        k_node_mlp<<<NB, 256, 0, stream>>>(x, nW1, nb1, nW2, nb2, x_t, N);
        k_edge_atomic<<<(E + 255)/256, 256, 0, stream>>>(pos, edge_attr, row, col, x_t,
                                                         eW1, eb1, eW2, eb2, s_acc, cntf, E);
        k_out_mlp<<<NB, 256, 0, stream>>>(s_acc, cntf, x, oW1, ob1, oW2, ob2, hout, N);
        k_bn_reduce<<<256, 256, 0, stream>>>(hout, sums, N*DD);
        k_bn_finalize<<<1, 64, 0, stream>>>(sums, gamma, beta, ssb, 1.0f/(float)N);
        k_bn_norm<<<(N*DD/4 + 255)/256, 256, 0, stream>>>(hout, ssb, N*DD/4);
    }
}

// Round 3
// 871.330 us; speedup vs baseline: 6.6407x; 1.3597x over previous
//
#include <hip/hip_runtime.h>
#include <math.h>

#define DD 64
#define EDA 16

typedef unsigned int u32;
typedef __attribute__((ext_vector_type(8))) short short8;
typedef __attribute__((ext_vector_type(4))) float f32x4;

static __device__ __forceinline__ float silu(float v) {
    return v / (1.0f + __expf(-v));
}
static __device__ __forceinline__ unsigned short f2bf(float f) {
    unsigned u = __float_as_uint(f);
    unsigned r = u + 0x7FFFu + ((u >> 16) & 1u);   // RNE
    return (unsigned short)(r >> 16);
}
static __device__ __forceinline__ unsigned pk2(float a, float b) {
    return (unsigned)f2bf(a) | ((unsigned)f2bf(b) << 16);
}
static __device__ __forceinline__ float bf2f(unsigned short u) {
    return __uint_as_float(((unsigned)u) << 16);
}

// ---------------- node MLP: x (N,64) f32 -> x_tb (N,64) bf16 ----------------
__global__ __launch_bounds__(256) void k_node_mlp(
    const float* __restrict__ x,
    const float* __restrict__ W1, const float* __restrict__ b1,
    const float* __restrict__ W2, const float* __restrict__ b2,
    unsigned short* __restrict__ x_tb, int n)
{
    __shared__ float sW1[DD*DD];
    __shared__ float sW2[DD*DD];
    __shared__ float sb1[DD], sb2[DD];
    for (int i = threadIdx.x; i < DD*DD; i += 256) { sW1[i] = W1[i]; sW2[i] = W2[i]; }
    if (threadIdx.x < DD) { sb1[threadIdx.x] = b1[threadIdx.x]; sb2[threadIdx.x] = b2[threadIdx.x]; }
    __syncthreads();
    int i = blockIdx.x * 256 + threadIdx.x;
    if (i >= n) return;

    float hid[DD];
    #pragma unroll
    for (int j = 0; j < DD; ++j) hid[j] = sb1[j];

    const float4* xr = (const float4*)(x + (size_t)i * DD);
    #pragma unroll
    for (int k4 = 0; k4 < DD/4; ++k4) {
        float4 v = xr[k4];
        float vals[4] = {v.x, v.y, v.z, v.w};
        #pragma unroll
        for (int u = 0; u < 4; ++u) {
            float xk = vals[u];
            const float4* wr = (const float4*)(sW1 + (4*k4+u)*DD);
            #pragma unroll
            for (int j4 = 0; j4 < DD/4; ++j4) {
                float4 w = wr[j4];
                hid[4*j4+0] = fmaf(xk, w.x, hid[4*j4+0]);
                hid[4*j4+1] = fmaf(xk, w.y, hid[4*j4+1]);
                hid[4*j4+2] = fmaf(xk, w.z, hid[4*j4+2]);
                hid[4*j4+3] = fmaf(xk, w.w, hid[4*j4+3]);
            }
        }
    }
    #pragma unroll
    for (int j = 0; j < DD; ++j) hid[j] = silu(hid[j]);

    float out[DD];
    #pragma unroll
    for (int j = 0; j < DD; ++j) out[j] = sb2[j];
    #pragma unroll 4
    for (int k = 0; k < DD; ++k) {
        float hk = hid[k];
        const float4* wr = (const float4*)(sW2 + k*DD);
        #pragma unroll
        for (int j4 = 0; j4 < DD/4; ++j4) {
            float4 w = wr[j4];
            out[4*j4+0] = fmaf(hk, w.x, out[4*j4+0]);
            out[4*j4+1] = fmaf(hk, w.y, out[4*j4+1]);
            out[4*j4+2] = fmaf(hk, w.z, out[4*j4+2]);
            out[4*j4+3] = fmaf(hk, w.w, out[4*j4+3]);
        }
    }
    unsigned short* orow = x_tb + (size_t)i * DD;
    #pragma unroll
    for (int q = 0; q < 8; ++q) {
        uint4 pk;
        pk.x = pk2(out[8*q+0], out[8*q+1]);
        pk.y = pk2(out[8*q+2], out[8*q+3]);
        pk.z = pk2(out[8*q+4], out[8*q+5]);
        pk.w = pk2(out[8*q+6], out[8*q+7]);
        ((uint4*)orow)[q] = pk;
    }
}

// ---------------- histogram + scans ----------------
__global__ __launch_bounds__(256) void k_hist(
    const int* __restrict__ col, u32* __restrict__ cnt, int n_e)
{
    int g = blockIdx.x * 256 + threadIdx.x;
    int base = g * 4;
    if (base + 3 < n_e) {
        int4 c = ((const int4*)col)[g];
        atomicAdd(&cnt[c.x], 1u);
        atomicAdd(&cnt[c.y], 1u);
        atomicAdd(&cnt[c.z], 1u);
        atomicAdd(&cnt[c.w], 1u);
    } else {
        for (int e = base; e < n_e; ++e) atomicAdd(&cnt[col[e]], 1u);
    }
}

__global__ __launch_bounds__(256) void k_scan1(
    const u32* __restrict__ cnt, u32* __restrict__ bsum, int n)
{
    __shared__ u32 s[256];
    int i = blockIdx.x * 256 + threadIdx.x;
    s[threadIdx.x] = (i < n) ? cnt[i] : 0u;
    __syncthreads();
    for (int o = 128; o > 0; o >>= 1) {
        if (threadIdx.x < o) s[threadIdx.x] += s[threadIdx.x + o];
        __syncthreads();
    }
    if (threadIdx.x == 0) bsum[blockIdx.x] = s[0];
}

__global__ __launch_bounds__(512) void k_scan2(
    const u32* __restrict__ bsum, u32* __restrict__ boff, int nb)
{
    __shared__ u32 s[512];
    int t = threadIdx.x;
    u32 v = (t < nb) ? bsum[t] : 0u;
    s[t] = v;
    __syncthreads();
    for (int o = 1; o < 512; o <<= 1) {
        u32 a = (t >= o) ? s[t - o] : 0u;
        __syncthreads();
        s[t] += a;
        __syncthreads();
    }
    if (t < nb) boff[t] = s[t] - v;
}

__global__ __launch_bounds__(256) void k_scan3(
    const u32* __restrict__ cnt, const u32* __restrict__ boff,
    u32* __restrict__ offs, u32* __restrict__ wp, int n)
{
    __shared__ u32 s[256];
    int t = threadIdx.x;
    int i = blockIdx.x * 256 + t;
    u32 v = (i < n) ? cnt[i] : 0u;
    s[t] = v;
    __syncthreads();
    for (int o = 1; o < 256; o <<= 1) {
        u32 a = (t >= o) ? s[t - o] : 0u;
        __syncthreads();
        s[t] += a;
        __syncthreads();
    }
    u32 off = boff[blockIdx.x] + s[t] - v;
    if (i < n) { offs[i] = off; wp[i] = off; }
}

// ---------------- weight pre-pack into MFMA B-fragment layout ----------------
// feature order (K=32): f[0..15]=attr[0..15], f[16..24]=SH[0..8], f[25..31]=0
// B-frag layout (16x16x32): lane l holds B[k=(l>>4)*8+j][n=l&15]
__global__ __launch_bounds__(256) void k_pack_w(
    const float* __restrict__ eW1, const float* __restrict__ eW2,
    unsigned short* __restrict__ w1pk, unsigned short* __restrict__ w2pk)
{
    int t = threadIdx.x;
    int nt = t >> 6, l = t & 63;
    int kc = l >> 4, n0 = l & 15;
    // W1: 4 frags (nt), entry t covers one (nt, lane)
    #pragma unroll
    for (int j = 0; j < 8; ++j) {
        int k = kc*8 + j;
        int orig = (k < 16) ? (9 + k) : ((k < 25) ? (k - 16) : -1);
        float v = (orig >= 0) ? eW1[orig*DD + nt*16 + n0] : 0.0f;
        w1pk[(size_t)t*8 + j] = f2bf(v);
    }
    // W2: 8 frags (s,nt)
    #pragma unroll
    for (int s = 0; s < 2; ++s) {
        #pragma unroll
        for (int j = 0; j < 8; ++j) {
            int k = s*32 + kc*8 + j;
            float v = eW2[k*DD + nt*16 + n0];
            w2pk[((size_t)(s*256 + t))*8 + j] = f2bf(v);
        }
    }
}

// ---------------- MFMA edge kernel ----------------
// block = 256 threads = 4 waves; each wave owns 16 edges.
__global__ __launch_bounds__(256) void k_edge_mfma(
    const float* __restrict__ pos,
    const float* __restrict__ edge_attr,
    const int* __restrict__ row, const int* __restrict__ col,
    const unsigned short* __restrict__ x_tb,
    const unsigned short* __restrict__ w1pk, const unsigned short* __restrict__ w2pk,
    const float* __restrict__ b1, const float* __restrict__ b2,
    u32* __restrict__ wp, unsigned short* __restrict__ msg, int n_e)
{
    __shared__ __align__(16) unsigned short hid_s[4][16*72];  // pad 72: 2-way banks only
    __shared__ __align__(16) unsigned short msg_s[4][16*72];
    __shared__ u32 p_s[4][16];

    const int tid  = threadIdx.x;
    const int wv   = tid >> 6;
    const int lane = tid & 63;
    const int kc   = lane >> 4;
    const int n0   = lane & 15;

    // weight fragments (L1-resident after first block on each CU)
    const short8* w1f = (const short8*)w1pk;
    const short8* w2f = (const short8*)w2pk;
    short8 bw1[4], bw2[2][4];
    #pragma unroll
    for (int nt = 0; nt < 4; ++nt) bw1[nt] = w1f[nt*64 + lane];
    #pragma unroll
    for (int s = 0; s < 2; ++s)
        #pragma unroll
        for (int nt = 0; nt < 4; ++nt) bw2[s][nt] = w2f[(s*4 + nt)*64 + lane];

    float b1v[4], b2v[4];
    #pragma unroll
    for (int nt = 0; nt < 4; ++nt) { b1v[nt] = b1[nt*16 + n0]; b2v[nt] = b2[nt*16 + n0]; }

    const int we = blockIdx.x*64 + wv*16;

    // ---- per-edge features (edge = we + n0; 4 lanes per edge, one k-chunk each)
    int ef  = we + n0;
    int efc = min(ef, n_e - 1);
    int rr  = row[efc], cc = col[efc];

    if (lane < 16) {
        u32 p = 0u;
        if (ef < n_e) p = atomicAdd(&wp[cc], 1u);   // early: latency hides under MLP
        p_s[wv][lane] = p;
    }

    float ax = pos[3*rr+0] - pos[3*cc+0];
    float ay = pos[3*rr+1] - pos[3*cc+1];
    float az = pos[3*rr+2] - pos[3*cc+2];
    float len = sqrtf(fmaf(ax,ax, fmaf(ay,ay, az*az)) + 1e-12f);
    float dx = ax/len, dy = ay/len, dz = az/len;
    float n2 = sqrtf(fmaf(dx,dx, fmaf(dy,dy, dz*dz)));
    float inv = 1.0f/(n2 + 1e-10f);
    dx *= inv; dy *= inv; dz *= inv;

    float sh[9];
    sh[0] = 0.28209479177387814f;
    sh[1] = 0.4886025119029199f*dy;
    sh[2] = 0.4886025119029199f*dz;
    sh[3] = 0.4886025119029199f*dx;
    sh[4] = 1.0925484305920792f*dx*dy;
    sh[5] = 1.0925484305920792f*dy*dz;
    sh[6] = 0.31539156525252005f*(3.0f*dz*dz - 1.0f);
    sh[7] = 1.0925484305920792f*dx*dz;
    sh[8] = 0.5462742152960396f*(dx*dx - dy*dy);

    float fv[8];
    #pragma unroll
    for (int j = 0; j < 8; ++j) fv[j] = 0.0f;
    if (kc < 2) {
        const float4* ap = (const float4*)(edge_attr + (size_t)efc*EDA + kc*8);
        float4 a0 = ap[0], a1 = ap[1];
        fv[0]=a0.x; fv[1]=a0.y; fv[2]=a0.z; fv[3]=a0.w;
        fv[4]=a1.x; fv[5]=a1.y; fv[6]=a1.z; fv[7]=a1.w;
    } else if (kc == 2) {
        #pragma unroll
        for (int j = 0; j < 8; ++j) fv[j] = sh[j];
    } else {
        fv[0] = sh[8];
    }

    short8 afrag;
    #pragma unroll
    for (int j = 0; j < 8; ++j) afrag[j] = (short)f2bf(fv[j]);

    // ---- GEMM 1: hid = F(16x32) x W1(32x64)
    f32x4 zz = {0.f, 0.f, 0.f, 0.f};
    f32x4 hacc[4];
    #pragma unroll
    for (int nt = 0; nt < 4; ++nt)
        hacc[nt] = __builtin_amdgcn_mfma_f32_16x16x32_bf16(afrag, bw1[nt], zz, 0, 0, 0);

    // bias + silu, write bf16 to per-wave LDS tile (C layout: row=(l>>4)*4+r, col=n0)
    const int rbase = (lane >> 4) * 4;
    #pragma unroll
    for (int nt = 0; nt < 4; ++nt) {
        #pragma unroll
        for (int r = 0; r < 4; ++r) {
            float v = hacc[nt][r] + b1v[nt];
            v = silu(v);
            hid_s[wv][(rbase + r)*72 + nt*16 + n0] = f2bf(v);
        }
    }
    __syncthreads();

    // ---- GEMM 2: out = hid(16x64) x W2(64x64); A-frags from LDS
    short8 a2_0 = *(const short8*)&hid_s[wv][n0*72 +  0 + kc*8];
    short8 a2_1 = *(const short8*)&hid_s[wv][n0*72 + 32 + kc*8];
    f32x4 oacc[4];
    #pragma unroll
    for (int nt = 0; nt < 4; ++nt) {
        oacc[nt] = __builtin_amdgcn_mfma_f32_16x16x32_bf16(a2_0, bw2[0][nt], zz, 0, 0, 0);
        oacc[nt] = __builtin_amdgcn_mfma_f32_16x16x32_bf16(a2_1, bw2[1][nt], oacc[nt], 0, 0, 0);
    }

    // ---- epilogue: msg = (out + b2) * x_tb[row[e]]  (bf16), staged in LDS
    #pragma unroll
    for (int r = 0; r < 4; ++r) {
        int er  = we + rbase + r;
        int erc = min(er, n_e - 1);
        int rw  = row[erc];
        const unsigned short* xrow = x_tb + (size_t)rw * DD;
        #pragma unroll
        for (int nt = 0; nt < 4; ++nt) {
            float xv = bf2f(xrow[nt*16 + n0]);
            float m  = (oacc[nt][r] + b2v[nt]) * xv;
            msg_s[wv][(rbase + r)*72 + nt*16 + n0] = f2bf(m);
        }
    }
    __syncthreads();

    // ---- cooperative full-line scatter: 4 lanes per edge write 2 x 64B lines
    int ei = lane >> 2, q = lane & 3;
    int e2 = we + ei;
    if (e2 < n_e) {
        u32 pp = p_s[wv][ei];
        const uint4* src = (const uint4*)&msg_s[wv][ei*72];
        uint4 v0 = src[q];
        uint4 v1 = src[q + 4];
        uint4* dst = (uint4*)(msg + (size_t)pp * DD);
        dst[q]     = v0;
        dst[q + 4] = v1;
    }
}

// ---------------- segment mean: wave per node, vectorized ----------------
__global__ __launch_bounds__(256) void k_agg(
    const unsigned short* __restrict__ msg,
    const u32* __restrict__ offs, const u32* __restrict__ cnt,
    float* __restrict__ agg, int n)
{
    int node = (blockIdx.x * 256 + threadIdx.x) >> 6;
    int lane = threadIdx.x & 63;
    if (node >= n) return;
    u32 off = offs[node], c = cnt[node];
    int fc = (lane & 7) * 8;   // feature chunk
    int rr = lane >> 3;        // row within group of 8
    float acc[8];
    #pragma unroll
    for (int j = 0; j < 8; ++j) acc[j] = 0.f;
    for (u32 i = rr; i < c; i += 8) {
        uint4 v = *(const uint4*)(msg + ((size_t)(off + i))*DD + fc);
        acc[0] += bf2f((unsigned short)(v.x));  acc[1] += bf2f((unsigned short)(v.x >> 16));
        acc[2] += bf2f((unsigned short)(v.y));  acc[3] += bf2f((unsigned short)(v.y >> 16));
        acc[4] += bf2f((unsigned short)(v.z));  acc[5] += bf2f((unsigned short)(v.z >> 16));
        acc[6] += bf2f((unsigned short)(v.w));  acc[7] += bf2f((unsigned short)(v.w >> 16));
    }
    #pragma unroll
    for (int m = 8; m <= 32; m <<= 1) {
        #pragma unroll
        for (int j = 0; j < 8; ++j) acc[j] += __shfl_xor(acc[j], m, 64);
    }
    if (lane < 8) {
        float invc = 1.0f / fmaxf((float)c, 1.0f);
        float4 o0 = {acc[0]*invc, acc[1]*invc, acc[2]*invc, acc[3]*invc};
        float4 o1 = {acc[4]*invc, acc[5]*invc, acc[6]*invc, acc[7]*invc};
        float4* dst = (float4*)(agg + (size_t)node*DD + fc);
        dst[0] = o0;
        dst[1] = o1;
    }
}

// ---------------- out MLP: h = MLP([agg, x]) -> d_out ----------------
__global__ __launch_bounds__(256) void k_out_mlp(
    const float* __restrict__ in0,
    const float* __restrict__ x,
    const float* __restrict__ W1, const float* __restrict__ b1,
    const float* __restrict__ W2, const float* __restrict__ b2,
    float* __restrict__ h, int n)
{
    __shared__ float sW1[2*DD*DD];
    __shared__ float sW2[DD*DD];
    __shared__ float sb1[DD], sb2[DD];
    for (int i = threadIdx.x; i < 2*DD*DD; i += 256) sW1[i] = W1[i];
    for (int i = threadIdx.x; i < DD*DD; i += 256) sW2[i] = W2[i];
    if (threadIdx.x < DD) { sb1[threadIdx.x] = b1[threadIdx.x]; sb2[threadIdx.x] = b2[threadIdx.x]; }
    __syncthreads();
    int i = blockIdx.x * 256 + threadIdx.x;
    if (i >= n) return;

    float hid[DD];
    #pragma unroll
    for (int j = 0; j < DD; ++j) hid[j] = sb1[j];

    const float4* sr = (const float4*)(in0 + (size_t)i * DD);
    #pragma unroll
    for (int k4 = 0; k4 < DD/4; ++k4) {
        float4 v = sr[k4];
        float vals[4] = {v.x, v.y, v.z, v.w};
        #pragma unroll
        for (int u = 0; u < 4; ++u) {
            float xk = vals[u];
            const float4* wr = (const float4*)(sW1 + (4*k4+u)*DD);
            #pragma unroll
            for (int j4 = 0; j4 < DD/4; ++j4) {
                float4 w = wr[j4];
                hid[4*j4+0] = fmaf(xk, w.x, hid[4*j4+0]);
                hid[4*j4+1] = fmaf(xk, w.y, hid[4*j4+1]);
                hid[4*j4+2] = fmaf(xk, w.z, hid[4*j4+2]);
                hid[4*j4+3] = fmaf(xk, w.w, hid[4*j4+3]);
            }
        }
    }
    const float4* xr = (const float4*)(x + (size_t)i * DD);
    #pragma unroll
    for (int k4 = 0; k4 < DD/4; ++k4) {
        float4 v = xr[k4];
        float vals[4] = {v.x, v.y, v.z, v.w};
        #pragma unroll
        for (int u = 0; u < 4; ++u) {
            float xk = vals[u];
            const float4* wr = (const float4*)(sW1 + (DD + 4*k4+u)*DD);
            #pragma unroll
            for (int j4 = 0; j4 < DD/4; ++j4) {
                float4 w = wr[j4];
                hid[4*j4+0] = fmaf(xk, w.x, hid[4*j4+0]);
                hid[4*j4+1] = fmaf(xk, w.y, hid[4*j4+1]);
                hid[4*j4+2] = fmaf(xk, w.z, hid[4*j4+2]);
                hid[4*j4+3] = fmaf(xk, w.w, hid[4*j4+3]);
            }
        }
    }
    #pragma unroll
    for (int j = 0; j < DD; ++j) hid[j] = silu(hid[j]);

    float out[DD];
    #pragma unroll
    for (int j = 0; j < DD; ++j) out[j] = sb2[j];
    #pragma unroll 4
    for (int k = 0; k < DD; ++k) {
        float hk = hid[k];
        const float4* wr = (const float4*)(sW2 + k*DD);
        #pragma unroll
        for (int j4 = 0; j4 < DD/4; ++j4) {
            float4 w = wr[j4];
            out[4*j4+0] = fmaf(hk, w.x, out[4*j4+0]);
            out[4*j4+1] = fmaf(hk, w.y, out[4*j4+1]);
            out[4*j4+2] = fmaf(hk, w.z, out[4*j4+2]);
            out[4*j4+3] = fmaf(hk, w.w, out[4*j4+3]);
        }
    }
    float4* orow = (float4*)(h + (size_t)i * DD);
    #pragma unroll
    for (int j4 = 0; j4 < DD/4; ++j4) {
        float4 o; o.x = out[4*j4]; o.y = out[4*j4+1]; o.z = out[4*j4+2]; o.w = out[4*j4+3];
        orow[j4] = o;
    }
}

// ---------------- BN ----------------
__global__ __launch_bounds__(256) void k_bn_reduce(
    const float* __restrict__ h, float* __restrict__ sums, int total)
{
    float s = 0.f, q = 0.f;
    int stride = gridDim.x * 256;
    for (int i = blockIdx.x*256 + threadIdx.x; i < total; i += stride) {
        float v = h[i];
        s += v; q = fmaf(v, v, q);
    }
    __shared__ float ls[256], lq[256];
    ls[threadIdx.x] = s; lq[threadIdx.x] = q;
    __syncthreads();
    if (threadIdx.x < DD) {
        float as = ls[threadIdx.x] + ls[threadIdx.x+64] + ls[threadIdx.x+128] + ls[threadIdx.x+192];
        float aq = lq[threadIdx.x] + lq[threadIdx.x+64] + lq[threadIdx.x+128] + lq[threadIdx.x+192];
        unsafeAtomicAdd(&sums[threadIdx.x], as);
        unsafeAtomicAdd(&sums[DD+threadIdx.x], aq);
    }
}

__global__ void k_bn_finalize(const float* __restrict__ sums,
                              const float* __restrict__ gamma, const float* __restrict__ beta,
                              float* __restrict__ ss, float inv_n)
{
    int j = threadIdx.x;   // 64 threads
    float m = sums[j] * inv_n;
    float var = sums[DD+j] * inv_n - m*m;
    float sc = gamma[j] * rsqrtf(var + 1e-5f);
    ss[j] = sc;
    ss[DD+j] = beta[j] - m*sc;
}

__global__ __launch_bounds__(256) void k_bn_norm(
    float* __restrict__ h, const float* __restrict__ ss, int total4)
{
    int g = blockIdx.x*256 + threadIdx.x;
    if (g >= total4) return;
    int f0 = (g*4) & (DD-1);
    float4 v = ((const float4*)h)[g];
    v.x = fmaf(v.x, ss[f0+0], ss[DD+f0+0]);
    v.y = fmaf(v.y, ss[f0+1], ss[DD+f0+1]);
    v.z = fmaf(v.z, ss[f0+2], ss[DD+f0+2]);
    v.w = fmaf(v.w, ss[f0+3], ss[DD+f0+3]);
    ((float4*)h)[g] = v;
}

static inline size_t al16(size_t v) { return (v + 15) & ~(size_t)15; }

extern "C" void kernel_launch(void* const* d_in, const int* in_sizes, int n_in,
                              void* d_out, int out_size, void* d_ws, size_t ws_size,
                              hipStream_t stream)
{
    const float* x         = (const float*)d_in[0];
    const float* pos       = (const float*)d_in[1];
    const float* edge_attr = (const float*)d_in[2];
    const int*   row       = (const int*)d_in[3];
    const int*   col       = (const int*)d_in[4];
    const float* nW1 = (const float*)d_in[5];
    const float* nb1 = (const float*)d_in[6];
    const float* nW2 = (const float*)d_in[7];
    const float* nb2 = (const float*)d_in[8];
    const float* eW1 = (const float*)d_in[9];
    const float* eb1 = (const float*)d_in[10];
    const float* eW2 = (const float*)d_in[11];
    const float* eb2 = (const float*)d_in[12];
    const float* oW1 = (const float*)d_in[13];
    const float* ob1 = (const float*)d_in[14];
    const float* oW2 = (const float*)d_in[15];
    const float* ob2 = (const float*)d_in[16];
    const float* gamma = (const float*)d_in[17];
    const float* beta  = (const float*)d_in[18];

    const int N = in_sizes[0] / DD;   // 100000
    const int E = in_sizes[3];        // 1600000
    const int NB = (N + 255) / 256;   // 391

    float* hout = (float*)d_out;
    char* ws = (char*)d_ws;

    size_t o_xtb  = 0;
    size_t o_msg  = o_xtb  + (size_t)N*DD*2;
    size_t o_agg  = o_msg  + (size_t)E*DD*2;
    size_t o_cnt  = o_agg  + (size_t)N*DD*4;
    size_t o_sums = o_cnt  + (size_t)N*4;       // 128 f32, memset with cnt
    size_t o_ss   = o_sums + 128*4;
    size_t o_offs = o_ss   + 128*4;
    size_t o_wp   = o_offs + (size_t)N*4;
    size_t o_bsum = o_wp   + (size_t)N*4;
    size_t o_boff = al16(o_bsum + (size_t)NB*4);
    size_t o_w1p  = al16(o_boff + (size_t)NB*4);
    size_t o_w2p  = o_w1p + 4*64*8*2;           // 4 KB
    size_t need   = o_w2p + 8*64*8*2;           // 8 KB

    if (ws_size < need) return;   // should not happen (need ~245 MB)

    unsigned short* x_tb = (unsigned short*)(ws + o_xtb);
    unsigned short* msg  = (unsigned short*)(ws + o_msg);
    float* agg  = (float*)(ws + o_agg);
    u32*   cnt  = (u32*)(ws + o_cnt);
    float* sums = (float*)(ws + o_sums);
    float* ssb  = (float*)(ws + o_ss);
    u32*   offs = (u32*)(ws + o_offs);
    u32*   wp   = (u32*)(ws + o_wp);
    u32*   bsum = (u32*)(ws + o_bsum);
    u32*   boff = (u32*)(ws + o_boff);
    unsigned short* w1pk = (unsigned short*)(ws + o_w1p);
    unsigned short* w2pk = (unsigned short*)(ws + o_w2p);

    hipMemsetAsync(cnt, 0, (size_t)N*4 + 128*4, stream);   // cnt + sums

    k_pack_w<<<1, 256, 0, stream>>>(eW1, eW2, w1pk, w2pk);
    k_hist <<<(E/4 + 255)/256, 256, 0, stream>>>(col, cnt, E);
    k_scan1<<<NB, 256, 0, stream>>>(cnt, bsum, N);
    k_scan2<<<1, 512, 0, stream>>>(bsum, boff, NB);
    k_scan3<<<NB, 256, 0, stream>>>(cnt, boff, offs, wp, N);
    k_node_mlp<<<NB, 256, 0, stream>>>(x, nW1, nb1, nW2, nb2, x_tb, N);
    k_edge_mfma<<<(E + 63)/64, 256, 0, stream>>>(pos, edge_attr, row, col, x_tb,
                                                 w1pk, w2pk, eb1, eb2, wp, msg, E);
    k_agg<<<(N*64 + 255)/256, 256, 0, stream>>>(msg, offs, cnt, agg, N);
    k_out_mlp<<<NB, 256, 0, stream>>>(agg, x, oW1, ob1, oW2, ob2, hout, N);
    k_bn_reduce<<<256, 256, 0, stream>>>(hout, sums, N*DD);
    k_bn_finalize<<<1, 64, 0, stream>>>(sums, gamma, beta, ssb, 1.0f/(float)N);
    k_bn_norm<<<(N*DD/4 + 255)/256, 256, 0, stream>>>(hout, ssb, N*DD/4);
}

// Round 4
// 409.948 us; speedup vs baseline: 14.1147x; 2.1255x over previous
//
#include <hip/hip_runtime.h>
#include <math.h>

#define DD 64
#define EDA 16

// packed B-fragment offsets (units of 64-lane short8 entries)
#define FR_E1 0
#define FR_E2 4
#define FR_N1 12
#define FR_N2 20
#define FR_O1 28
#define FR_O2 44
#define FR_TOT 52

typedef unsigned int u32;
typedef __attribute__((ext_vector_type(8))) short short8;
typedef __attribute__((ext_vector_type(4))) float f32x4;

static __device__ __forceinline__ float silu(float v) {
    return v / (1.0f + __expf(-v));
}
static __device__ __forceinline__ unsigned short f2bf(float f) {
    unsigned u = __float_as_uint(f);
    unsigned r = u + 0x7FFFu + ((u >> 16) & 1u);   // RNE
    return (unsigned short)(r >> 16);
}
static __device__ __forceinline__ float bf2f(unsigned short u) {
    return __uint_as_float(((unsigned)u) << 16);
}

// ---------------- weight pre-pack into MFMA B-fragment layout ----------------
// B-frag (16x16x32): lane l holds B[k = s*32 + (l>>4)*8 + j][n = nt*16 + (l&15)]
// edge W1 feature order (K=32): k0..15=attr, k16..24=SH, k25..31=zero
__global__ __launch_bounds__(256) void k_pack_w(
    const float* __restrict__ eW1, const float* __restrict__ eW2,
    const float* __restrict__ nW1, const float* __restrict__ nW2,
    const float* __restrict__ oW1, const float* __restrict__ oW2,
    unsigned short* __restrict__ wpk)
{
    int t = threadIdx.x;
    int nt = t >> 6, l = t & 63;
    int kc = l >> 4, n0 = l & 15;

    // edge W1 (1 s-chunk, reordered)
    #pragma unroll
    for (int j = 0; j < 8; ++j) {
        int k = kc*8 + j;
        int orig = (k < 16) ? (9 + k) : ((k < 25) ? (k - 16) : -1);
        float v = (orig >= 0) ? eW1[orig*DD + nt*16 + n0] : 0.0f;
        wpk[((size_t)((FR_E1 + nt)*64 + l))*8 + j] = f2bf(v);
    }
    // edge W2 / node W1 / node W2 (2 s-chunks each, K=64)
    #pragma unroll
    for (int s = 0; s < 2; ++s) {
        #pragma unroll
        for (int j = 0; j < 8; ++j) {
            int k = s*32 + kc*8 + j;
            wpk[((size_t)((FR_E2 + s*4 + nt)*64 + l))*8 + j] = f2bf(eW2[k*DD + nt*16 + n0]);
            wpk[((size_t)((FR_N1 + s*4 + nt)*64 + l))*8 + j] = f2bf(nW1[k*DD + nt*16 + n0]);
            wpk[((size_t)((FR_N2 + s*4 + nt)*64 + l))*8 + j] = f2bf(nW2[k*DD + nt*16 + n0]);
            wpk[((size_t)((FR_O2 + s*4 + nt)*64 + l))*8 + j] = f2bf(oW2[k*DD + nt*16 + n0]);
        }
    }
    // out W1 (4 s-chunks, K=128)
    #pragma unroll
    for (int s = 0; s < 4; ++s) {
        #pragma unroll
        for (int j = 0; j < 8; ++j) {
            int k = s*32 + kc*8 + j;
            wpk[((size_t)((FR_O1 + s*4 + nt)*64 + l))*8 + j] = f2bf(oW1[k*DD + nt*16 + n0]);
        }
    }
}

// ---------------- histogram + scans ----------------
__global__ __launch_bounds__(256) void k_hist(
    const int* __restrict__ col, u32* __restrict__ cnt, int n_e)
{
    int g = blockIdx.x * 256 + threadIdx.x;
    int base = g * 4;
    if (base + 3 < n_e) {
        int4 c = ((const int4*)col)[g];
        atomicAdd(&cnt[c.x], 1u);
        atomicAdd(&cnt[c.y], 1u);
        atomicAdd(&cnt[c.z], 1u);
        atomicAdd(&cnt[c.w], 1u);
    } else {
        for (int e = base; e < n_e; ++e) atomicAdd(&cnt[col[e]], 1u);
    }
}

__global__ __launch_bounds__(256) void k_scan1(
    const u32* __restrict__ cnt, u32* __restrict__ bsum, int n)
{
    __shared__ u32 s[256];
    int i = blockIdx.x * 256 + threadIdx.x;
    s[threadIdx.x] = (i < n) ? cnt[i] : 0u;
    __syncthreads();
    for (int o = 128; o > 0; o >>= 1) {
        if (threadIdx.x < o) s[threadIdx.x] += s[threadIdx.x + o];
        __syncthreads();
    }
    if (threadIdx.x == 0) bsum[blockIdx.x] = s[0];
}

__global__ __launch_bounds__(512) void k_scan2(
    const u32* __restrict__ bsum, u32* __restrict__ boff, int nb)
{
    __shared__ u32 s[512];
    int t = threadIdx.x;
    u32 v = (t < nb) ? bsum[t] : 0u;
    s[t] = v;
    __syncthreads();
    for (int o = 1; o < 512; o <<= 1) {
        u32 a = (t >= o) ? s[t - o] : 0u;
        __syncthreads();
        s[t] += a;
        __syncthreads();
    }
    if (t < nb) boff[t] = s[t] - v;
}

__global__ __launch_bounds__(256) void k_scan3(
    const u32* __restrict__ cnt, const u32* __restrict__ boff,
    u32* __restrict__ offs, u32* __restrict__ wp, int n)
{
    __shared__ u32 s[256];
    int t = threadIdx.x;
    int i = blockIdx.x * 256 + t;
    u32 v = (i < n) ? cnt[i] : 0u;
    s[t] = v;
    __syncthreads();
    for (int o = 1; o < 256; o <<= 1) {
        u32 a = (t >= o) ? s[t - o] : 0u;
        __syncthreads();
        s[t] += a;
        __syncthreads();
    }
    u32 off = boff[blockIdx.x] + s[t] - v;
    if (i < n) { offs[i] = off; wp[i] = off; }
}

// ---------------- MFMA node MLP: x (N,64) f32 -> x_tb (N,64) bf16 ----------------
__global__ __launch_bounds__(256, 2) void k_node_mfma(
    const float* __restrict__ x,
    const unsigned short* __restrict__ wpk,
    const float* __restrict__ b1, const float* __restrict__ b2,
    unsigned short* __restrict__ x_tb, int n)
{
    __shared__ __align__(16) unsigned short tile[4][16*72];
    const int tid  = threadIdx.x;
    const int wv   = tid >> 6;
    const int lane = tid & 63;
    const int kc   = lane >> 4;
    const int n0   = lane & 15;
    const int rbase = kc * 4;

    const short8* fb = (const short8*)wpk;
    short8 bw1[2][4], bw2[2][4];
    #pragma unroll
    for (int s = 0; s < 2; ++s)
        #pragma unroll
        for (int nt = 0; nt < 4; ++nt) {
            bw1[s][nt] = fb[(FR_N1 + s*4 + nt)*64 + lane];
            bw2[s][nt] = fb[(FR_N2 + s*4 + nt)*64 + lane];
        }
    float b1v[4], b2v[4];
    #pragma unroll
    for (int nt = 0; nt < 4; ++nt) { b1v[nt] = b1[nt*16 + n0]; b2v[nt] = b2[nt*16 + n0]; }

    const int base = blockIdx.x*64 + wv*16;
    int rc = min(base + n0, n - 1);
    const float* xr = x + (size_t)rc * DD;

    short8 a[2];
    #pragma unroll
    for (int m = 0; m < 2; ++m) {
        float4 u0 = *(const float4*)(xr + m*32 + kc*8);
        float4 u1 = *(const float4*)(xr + m*32 + kc*8 + 4);
        a[m][0] = (short)f2bf(u0.x); a[m][1] = (short)f2bf(u0.y);
        a[m][2] = (short)f2bf(u0.z); a[m][3] = (short)f2bf(u0.w);
        a[m][4] = (short)f2bf(u1.x); a[m][5] = (short)f2bf(u1.y);
        a[m][6] = (short)f2bf(u1.z); a[m][7] = (short)f2bf(u1.w);
    }

    f32x4 zz = {0.f, 0.f, 0.f, 0.f};
    f32x4 hacc[4] = {zz, zz, zz, zz};
    #pragma unroll
    for (int m = 0; m < 2; ++m)
        #pragma unroll
        for (int nt = 0; nt < 4; ++nt)
            hacc[nt] = __builtin_amdgcn_mfma_f32_16x16x32_bf16(a[m], bw1[m][nt], hacc[nt], 0, 0, 0);

    #pragma unroll
    for (int nt = 0; nt < 4; ++nt)
        #pragma unroll
        for (int r = 0; r < 4; ++r)
            tile[wv][(rbase + r)*72 + nt*16 + n0] = f2bf(silu(hacc[nt][r] + b1v[nt]));
    __syncthreads();

    short8 a2_0 = *(const short8*)&tile[wv][n0*72 +  0 + kc*8];
    short8 a2_1 = *(const short8*)&tile[wv][n0*72 + 32 + kc*8];
    f32x4 oacc[4];
    #pragma unroll
    for (int nt = 0; nt < 4; ++nt) {
        oacc[nt] = __builtin_amdgcn_mfma_f32_16x16x32_bf16(a2_0, bw2[0][nt], zz, 0, 0, 0);
        oacc[nt] = __builtin_amdgcn_mfma_f32_16x16x32_bf16(a2_1, bw2[1][nt], oacc[nt], 0, 0, 0);
    }
    __syncthreads();

    #pragma unroll
    for (int nt = 0; nt < 4; ++nt)
        #pragma unroll
        for (int r = 0; r < 4; ++r)
            tile[wv][(rbase + r)*72 + nt*16 + n0] = f2bf(oacc[nt][r] + b2v[nt]);
    __syncthreads();

    int ei = lane >> 2, q = lane & 3;
    int er = base + ei;
    if (er < n) {
        uint4* dst = (uint4*)(x_tb + (size_t)er * DD);
        dst[q]     = *(const uint4*)&tile[wv][ei*72 + q*8];
        dst[q + 4] = *(const uint4*)&tile[wv][ei*72 + (q + 4)*8];
    }
}

// ---------------- MFMA edge kernel ----------------
__global__ __launch_bounds__(256) void k_edge_mfma(
    const float* __restrict__ pos,
    const float* __restrict__ edge_attr,
    const int* __restrict__ row, const int* __restrict__ col,
    const unsigned short* __restrict__ x_tb,
    const unsigned short* __restrict__ wpk,
    const float* __restrict__ b1, const float* __restrict__ b2,
    u32* __restrict__ wp, unsigned short* __restrict__ msg, int n_e)
{
    __shared__ __align__(16) unsigned short hid_s[4][16*72];
    __shared__ __align__(16) unsigned short msg_s[4][16*72];
    __shared__ u32 p_s[4][16];

    const int tid  = threadIdx.x;
    const int wv   = tid >> 6;
    const int lane = tid & 63;
    const int kc   = lane >> 4;
    const int n0   = lane & 15;

    const short8* fb = (const short8*)wpk;
    short8 bw1[4], bw2[2][4];
    #pragma unroll
    for (int nt = 0; nt < 4; ++nt) bw1[nt] = fb[(FR_E1 + nt)*64 + lane];
    #pragma unroll
    for (int s = 0; s < 2; ++s)
        #pragma unroll
        for (int nt = 0; nt < 4; ++nt) bw2[s][nt] = fb[(FR_E2 + s*4 + nt)*64 + lane];

    float b1v[4], b2v[4];
    #pragma unroll
    for (int nt = 0; nt < 4; ++nt) { b1v[nt] = b1[nt*16 + n0]; b2v[nt] = b2[nt*16 + n0]; }

    const int we = blockIdx.x*64 + wv*16;

    int ef  = we + n0;
    int efc = min(ef, n_e - 1);
    int rr  = row[efc], cc = col[efc];

    if (lane < 16) {
        u32 p = 0u;
        if (ef < n_e) p = atomicAdd(&wp[cc], 1u);
        p_s[wv][lane] = p;
    }

    float ax = pos[3*rr+0] - pos[3*cc+0];
    float ay = pos[3*rr+1] - pos[3*cc+1];
    float az = pos[3*rr+2] - pos[3*cc+2];
    float len = sqrtf(fmaf(ax,ax, fmaf(ay,ay, az*az)) + 1e-12f);
    float dx = ax/len, dy = ay/len, dz = az/len;
    float n2 = sqrtf(fmaf(dx,dx, fmaf(dy,dy, dz*dz)));
    float inv = 1.0f/(n2 + 1e-10f);
    dx *= inv; dy *= inv; dz *= inv;

    float sh[9];
    sh[0] = 0.28209479177387814f;
    sh[1] = 0.4886025119029199f*dy;
    sh[2] = 0.4886025119029199f*dz;
    sh[3] = 0.4886025119029199f*dx;
    sh[4] = 1.0925484305920792f*dx*dy;
    sh[5] = 1.0925484305920792f*dy*dz;
    sh[6] = 0.31539156525252005f*(3.0f*dz*dz - 1.0f);
    sh[7] = 1.0925484305920792f*dx*dz;
    sh[8] = 0.5462742152960396f*(dx*dx - dy*dy);

    float fv[8];
    #pragma unroll
    for (int j = 0; j < 8; ++j) fv[j] = 0.0f;
    if (kc < 2) {
        const float4* ap = (const float4*)(edge_attr + (size_t)efc*EDA + kc*8);
        float4 a0 = ap[0], a1 = ap[1];
        fv[0]=a0.x; fv[1]=a0.y; fv[2]=a0.z; fv[3]=a0.w;
        fv[4]=a1.x; fv[5]=a1.y; fv[6]=a1.z; fv[7]=a1.w;
    } else if (kc == 2) {
        #pragma unroll
        for (int j = 0; j < 8; ++j) fv[j] = sh[j];
    } else {
        fv[0] = sh[8];
    }

    short8 afrag;
    #pragma unroll
    for (int j = 0; j < 8; ++j) afrag[j] = (short)f2bf(fv[j]);

    f32x4 zz = {0.f, 0.f, 0.f, 0.f};
    f32x4 hacc[4];
    #pragma unroll
    for (int nt = 0; nt < 4; ++nt)
        hacc[nt] = __builtin_amdgcn_mfma_f32_16x16x32_bf16(afrag, bw1[nt], zz, 0, 0, 0);

    const int rbase = kc * 4;
    #pragma unroll
    for (int nt = 0; nt < 4; ++nt) {
        #pragma unroll
        for (int r = 0; r < 4; ++r) {
            float v = hacc[nt][r] + b1v[nt];
            v = silu(v);
            hid_s[wv][(rbase + r)*72 + nt*16 + n0] = f2bf(v);
        }
    }
    __syncthreads();

    short8 a2_0 = *(const short8*)&hid_s[wv][n0*72 +  0 + kc*8];
    short8 a2_1 = *(const short8*)&hid_s[wv][n0*72 + 32 + kc*8];
    f32x4 oacc[4];
    #pragma unroll
    for (int nt = 0; nt < 4; ++nt) {
        oacc[nt] = __builtin_amdgcn_mfma_f32_16x16x32_bf16(a2_0, bw2[0][nt], zz, 0, 0, 0);
        oacc[nt] = __builtin_amdgcn_mfma_f32_16x16x32_bf16(a2_1, bw2[1][nt], oacc[nt], 0, 0, 0);
    }

    #pragma unroll
    for (int r = 0; r < 4; ++r) {
        int er  = we + rbase + r;
        int erc = min(er, n_e - 1);
        int rw  = row[erc];
        const unsigned short* xrow = x_tb + (size_t)rw * DD;
        #pragma unroll
        for (int nt = 0; nt < 4; ++nt) {
            float xv = bf2f(xrow[nt*16 + n0]);
            float m  = (oacc[nt][r] + b2v[nt]) * xv;
            msg_s[wv][(rbase + r)*72 + nt*16 + n0] = f2bf(m);
        }
    }
    __syncthreads();

    int ei = lane >> 2, q = lane & 3;
    int e2 = we + ei;
    if (e2 < n_e) {
        u32 pp = p_s[wv][ei];
        const uint4* src = (const uint4*)&msg_s[wv][ei*72];
        uint4 v0 = src[q];
        uint4 v1 = src[q + 4];
        uint4* dst = (uint4*)(msg + (size_t)pp * DD);
        dst[q]     = v0;
        dst[q + 4] = v1;
    }
}

// ---------------- segment mean: wave per node ----------------
__global__ __launch_bounds__(256) void k_agg(
    const unsigned short* __restrict__ msg,
    const u32* __restrict__ offs, const u32* __restrict__ cnt,
    float* __restrict__ agg, int n)
{
    int node = (blockIdx.x * 256 + threadIdx.x) >> 6;
    int lane = threadIdx.x & 63;
    if (node >= n) return;
    u32 off = offs[node], c = cnt[node];
    int fc = (lane & 7) * 8;
    int rr = lane >> 3;
    float acc[8];
    #pragma unroll
    for (int j = 0; j < 8; ++j) acc[j] = 0.f;
    for (u32 i = rr; i < c; i += 8) {
        uint4 v = *(const uint4*)(msg + ((size_t)(off + i))*DD + fc);
        acc[0] += bf2f((unsigned short)(v.x));  acc[1] += bf2f((unsigned short)(v.x >> 16));
        acc[2] += bf2f((unsigned short)(v.y));  acc[3] += bf2f((unsigned short)(v.y >> 16));
        acc[4] += bf2f((unsigned short)(v.z));  acc[5] += bf2f((unsigned short)(v.z >> 16));
        acc[6] += bf2f((unsigned short)(v.w));  acc[7] += bf2f((unsigned short)(v.w >> 16));
    }
    #pragma unroll
    for (int m = 8; m <= 32; m <<= 1) {
        #pragma unroll
        for (int j = 0; j < 8; ++j) acc[j] += __shfl_xor(acc[j], m, 64);
    }
    if (lane < 8) {
        float invc = 1.0f / fmaxf((float)c, 1.0f);
        float4 o0 = {acc[0]*invc, acc[1]*invc, acc[2]*invc, acc[3]*invc};
        float4 o1 = {acc[4]*invc, acc[5]*invc, acc[6]*invc, acc[7]*invc};
        float4* dst = (float4*)(agg + (size_t)node*DD + fc);
        dst[0] = o0;
        dst[1] = o1;
    }
}

// ---------------- MFMA out MLP + fused BN partial sums ----------------
__global__ __launch_bounds__(256, 2) void k_out_mfma(
    const float* __restrict__ agg, const float* __restrict__ x,
    const unsigned short* __restrict__ wpk,
    const float* __restrict__ b1, const float* __restrict__ b2,
    float* __restrict__ h, float* __restrict__ sums, int n)
{
    __shared__ __align__(16) unsigned short htile[4][16*72];
    __shared__ __align__(16) float otile[4][16*68];
    const int tid  = threadIdx.x;
    const int wv   = tid >> 6;
    const int lane = tid & 63;
    const int kc   = lane >> 4;
    const int n0   = lane & 15;
    const int rbase = kc * 4;

    const short8* fb = (const short8*)wpk;
    short8 bw1[4][4], bw2[2][4];
    #pragma unroll
    for (int s = 0; s < 4; ++s)
        #pragma unroll
        for (int nt = 0; nt < 4; ++nt) bw1[s][nt] = fb[(FR_O1 + s*4 + nt)*64 + lane];
    #pragma unroll
    for (int s = 0; s < 2; ++s)
        #pragma unroll
        for (int nt = 0; nt < 4; ++nt) bw2[s][nt] = fb[(FR_O2 + s*4 + nt)*64 + lane];

    float b1v[4], b2v[4];
    #pragma unroll
    for (int nt = 0; nt < 4; ++nt) { b1v[nt] = b1[nt*16 + n0]; b2v[nt] = b2[nt*16 + n0]; }

    const int base = blockIdx.x*64 + wv*16;
    int rc = min(base + n0, n - 1);
    const float* ar = agg + (size_t)rc * DD;
    const float* xr = x   + (size_t)rc * DD;

    short8 a[4];
    #pragma unroll
    for (int m = 0; m < 4; ++m) {
        const float* src = (m < 2) ? (ar + m*32 + kc*8) : (xr + (m-2)*32 + kc*8);
        float4 u0 = *(const float4*)(src);
        float4 u1 = *(const float4*)(src + 4);
        a[m][0] = (short)f2bf(u0.x); a[m][1] = (short)f2bf(u0.y);
        a[m][2] = (short)f2bf(u0.z); a[m][3] = (short)f2bf(u0.w);
        a[m][4] = (short)f2bf(u1.x); a[m][5] = (short)f2bf(u1.y);
        a[m][6] = (short)f2bf(u1.z); a[m][7] = (short)f2bf(u1.w);
    }

    f32x4 zz = {0.f, 0.f, 0.f, 0.f};
    f32x4 hacc[4] = {zz, zz, zz, zz};
    #pragma unroll
    for (int m = 0; m < 4; ++m)
        #pragma unroll
        for (int nt = 0; nt < 4; ++nt)
            hacc[nt] = __builtin_amdgcn_mfma_f32_16x16x32_bf16(a[m], bw1[m][nt], hacc[nt], 0, 0, 0);

    #pragma unroll
    for (int nt = 0; nt < 4; ++nt)
        #pragma unroll
        for (int r = 0; r < 4; ++r)
            htile[wv][(rbase + r)*72 + nt*16 + n0] = f2bf(silu(hacc[nt][r] + b1v[nt]));
    __syncthreads();

    short8 a2_0 = *(const short8*)&htile[wv][n0*72 +  0 + kc*8];
    short8 a2_1 = *(const short8*)&htile[wv][n0*72 + 32 + kc*8];
    f32x4 oacc[4];
    #pragma unroll
    for (int nt = 0; nt < 4; ++nt) {
        oacc[nt] = __builtin_amdgcn_mfma_f32_16x16x32_bf16(a2_0, bw2[0][nt], zz, 0, 0, 0);
        oacc[nt] = __builtin_amdgcn_mfma_f32_16x16x32_bf16(a2_1, bw2[1][nt], oacc[nt], 0, 0, 0);
    }

    #pragma unroll
    for (int nt = 0; nt < 4; ++nt)
        #pragma unroll
        for (int r = 0; r < 4; ++r)
            otile[wv][(rbase + r)*68 + nt*16 + n0] = oacc[nt][r] + b2v[nt];
    __syncthreads();

    // store h rows (each wave writes its own 16 rows)
    int ei = lane >> 2, q = lane & 3;
    int er = base + ei;
    if (er < n) {
        float4* dst = (float4*)(h + (size_t)er * DD);
        #pragma unroll
        for (int k = 0; k < 4; ++k)
            dst[q + 4*k] = *(const float4*)&otile[wv][ei*68 + (q + 4*k)*4];
    }

    // fused BN partial sums (one wave reduces the whole block tile)
    if (tid < 64) {
        int f = tid;
        float s = 0.f, qq = 0.f;
        #pragma unroll
        for (int w = 0; w < 4; ++w) {
            int base_w = blockIdx.x*64 + w*16;
            int nv = n - base_w;
            nv = nv < 0 ? 0 : (nv > 16 ? 16 : nv);
            for (int r = 0; r < nv; ++r) {
                float v = otile[w][r*68 + f];
                s += v; qq = fmaf(v, v, qq);
            }
        }
        unsafeAtomicAdd(&sums[f], s);
        unsafeAtomicAdd(&sums[DD + f], qq);
    }
}

// ---------------- BN finalize + normalize ----------------
__global__ void k_bn_finalize(const float* __restrict__ sums,
                              const float* __restrict__ gamma, const float* __restrict__ beta,
                              float* __restrict__ ss, float inv_n)
{
    int j = threadIdx.x;   // 64 threads
    float m = sums[j] * inv_n;
    float var = sums[DD+j] * inv_n - m*m;
    float sc = gamma[j] * rsqrtf(var + 1e-5f);
    ss[j] = sc;
    ss[DD+j] = beta[j] - m*sc;
}

__global__ __launch_bounds__(256) void k_bn_norm(
    float* __restrict__ h, const float* __restrict__ ss, int total4)
{
    int g = blockIdx.x*256 + threadIdx.x;
    if (g >= total4) return;
    int f0 = (g*4) & (DD-1);
    float4 v = ((const float4*)h)[g];
    v.x = fmaf(v.x, ss[f0+0], ss[DD+f0+0]);
    v.y = fmaf(v.y, ss[f0+1], ss[DD+f0+1]);
    v.z = fmaf(v.z, ss[f0+2], ss[DD+f0+2]);
    v.w = fmaf(v.w, ss[f0+3], ss[DD+f0+3]);
    ((float4*)h)[g] = v;
}

static inline size_t al16(size_t v) { return (v + 15) & ~(size_t)15; }

extern "C" void kernel_launch(void* const* d_in, const int* in_sizes, int n_in,
                              void* d_out, int out_size, void* d_ws, size_t ws_size,
                              hipStream_t stream)
{
    const float* x         = (const float*)d_in[0];
    const float* pos       = (const float*)d_in[1];
    const float* edge_attr = (const float*)d_in[2];
    const int*   row       = (const int*)d_in[3];
    const int*   col       = (const int*)d_in[4];
    const float* nW1 = (const float*)d_in[5];
    const float* nb1 = (const float*)d_in[6];
    const float* nW2 = (const float*)d_in[7];
    const float* nb2 = (const float*)d_in[8];
    const float* eW1 = (const float*)d_in[9];
    const float* eb1 = (const float*)d_in[10];
    const float* eW2 = (const float*)d_in[11];
    const float* eb2 = (const float*)d_in[12];
    const float* oW1 = (const float*)d_in[13];
    const float* ob1 = (const float*)d_in[14];
    const float* oW2 = (const float*)d_in[15];
    const float* ob2 = (const float*)d_in[16];
    const float* gamma = (const float*)d_in[17];
    const float* beta  = (const float*)d_in[18];

    const int N = in_sizes[0] / DD;   // 100000
    const int E = in_sizes[3];        // 1600000
    const int NB = (N + 255) / 256;   // 391

    float* hout = (float*)d_out;
    char* ws = (char*)d_ws;

    size_t o_xtb  = 0;
    size_t o_msg  = o_xtb  + (size_t)N*DD*2;
    size_t o_agg  = o_msg  + (size_t)E*DD*2;
    size_t o_cnt  = o_agg  + (size_t)N*DD*4;
    size_t o_sums = o_cnt  + (size_t)N*4;       // 128 f32, memset with cnt
    size_t o_ss   = o_sums + 128*4;
    size_t o_offs = o_ss   + 128*4;
    size_t o_wp   = o_offs + (size_t)N*4;
    size_t o_bsum = o_wp   + (size_t)N*4;
    size_t o_boff = al16(o_bsum + (size_t)NB*4);
    size_t o_wpk  = al16(o_boff + (size_t)NB*4);
    size_t need   = o_wpk + (size_t)FR_TOT*64*8*2;

    if (ws_size < need) return;

    unsigned short* x_tb = (unsigned short*)(ws + o_xtb);
    unsigned short* msg  = (unsigned short*)(ws + o_msg);
    float* agg  = (float*)(ws + o_agg);
    u32*   cnt  = (u32*)(ws + o_cnt);
    float* sums = (float*)(ws + o_sums);
    float* ssb  = (float*)(ws + o_ss);
    u32*   offs = (u32*)(ws + o_offs);
    u32*   wp   = (u32*)(ws + o_wp);
    u32*   bsum = (u32*)(ws + o_bsum);
    u32*   boff = (u32*)(ws + o_boff);
    unsigned short* wpk = (unsigned short*)(ws + o_wpk);

    hipMemsetAsync(cnt, 0, (size_t)N*4 + 128*4, stream);   // cnt + sums

    k_pack_w<<<1, 256, 0, stream>>>(eW1, eW2, nW1, nW2, oW1, oW2, wpk);
    k_hist <<<(E/4 + 255)/256, 256, 0, stream>>>(col, cnt, E);
    k_scan1<<<NB, 256, 0, stream>>>(cnt, bsum, N);
    k_scan2<<<1, 512, 0, stream>>>(bsum, boff, NB);
    k_scan3<<<NB, 256, 0, stream>>>(cnt, boff, offs, wp, N);
    k_node_mfma<<<(N + 63)/64, 256, 0, stream>>>(x, wpk, nb1, nb2, x_tb, N);
    k_edge_mfma<<<(E + 63)/64, 256, 0, stream>>>(pos, edge_attr, row, col, x_tb,
                                                 wpk, eb1, eb2, wp, msg, E);
    k_agg<<<(N*64 + 255)/256, 256, 0, stream>>>(msg, offs, cnt, agg, N);
    k_out_mfma<<<(N + 63)/64, 256, 0, stream>>>(agg, x, wpk, ob1, ob2, hout, sums, N);
    k_bn_finalize<<<1, 64, 0, stream>>>(sums, gamma, beta, ssb, 1.0f/(float)N);
    k_bn_norm<<<(N*DD/4 + 255)/256, 256, 0, stream>>>(hout, ssb, N*DD/4);
}

// Round 5
// 359.075 us; speedup vs baseline: 16.1144x; 1.1417x over previous
//
#include <hip/hip_runtime.h>
#include <math.h>

#define DD 64
#define EDA 16

// packed B-fragment offsets (units of 64-lane short8 entries)
#define FR_E1 0
#define FR_E2 4
#define FR_N1 12
#define FR_N2 20
#define FR_O1 28
#define FR_O2 44
#define FR_TOT 52

#define PADH 72   // hid bf16 LDS row stride (ushort)
#define PADF 68   // msg f32  LDS row stride (float)

typedef unsigned int u32;
typedef __attribute__((ext_vector_type(8))) short short8;
typedef __attribute__((ext_vector_type(4))) float f32x4;

static __device__ __forceinline__ float silu(float v) {
    return v / (1.0f + __expf(-v));
}
static __device__ __forceinline__ unsigned short f2bf(float f) {
    unsigned u = __float_as_uint(f);
    unsigned r = u + 0x7FFFu + ((u >> 16) & 1u);   // RNE
    return (unsigned short)(r >> 16);
}
static __device__ __forceinline__ float bf2f(unsigned short u) {
    return __uint_as_float(((unsigned)u) << 16);
}
// packed f32x2 -> bf16x2 (RNE), single instruction on gfx950
static __device__ __forceinline__ unsigned cvt_pk_bf16(float lo, float hi) {
    unsigned r;
    asm("v_cvt_pk_bf16_f32 %0, %1, %2" : "=v"(r) : "v"(lo), "v"(hi));
    return r;
}

// ---------------- weight pre-pack into MFMA B-fragment layout ----------------
// B-frag (16x16x32): lane l holds B[k = s*32 + (l>>4)*8 + j][n = nt*16 + (l&15)]
// edge W1 feature order (K=32): k0..15=attr, k16..24=SH, k25..31=zero
__global__ __launch_bounds__(256) void k_pack_w(
    const float* __restrict__ eW1, const float* __restrict__ eW2,
    const float* __restrict__ nW1, const float* __restrict__ nW2,
    const float* __restrict__ oW1, const float* __restrict__ oW2,
    unsigned short* __restrict__ wpk)
{
    int t = threadIdx.x;
    int nt = t >> 6, l = t & 63;
    int kc = l >> 4, n0 = l & 15;

    #pragma unroll
    for (int j = 0; j < 8; ++j) {
        int k = kc*8 + j;
        int orig = (k < 16) ? (9 + k) : ((k < 25) ? (k - 16) : -1);
        float v = (orig >= 0) ? eW1[orig*DD + nt*16 + n0] : 0.0f;
        wpk[((size_t)((FR_E1 + nt)*64 + l))*8 + j] = f2bf(v);
    }
    #pragma unroll
    for (int s = 0; s < 2; ++s) {
        #pragma unroll
        for (int j = 0; j < 8; ++j) {
            int k = s*32 + kc*8 + j;
            wpk[((size_t)((FR_E2 + s*4 + nt)*64 + l))*8 + j] = f2bf(eW2[k*DD + nt*16 + n0]);
            wpk[((size_t)((FR_N1 + s*4 + nt)*64 + l))*8 + j] = f2bf(nW1[k*DD + nt*16 + n0]);
            wpk[((size_t)((FR_N2 + s*4 + nt)*64 + l))*8 + j] = f2bf(nW2[k*DD + nt*16 + n0]);
            wpk[((size_t)((FR_O2 + s*4 + nt)*64 + l))*8 + j] = f2bf(oW2[k*DD + nt*16 + n0]);
        }
    }
    #pragma unroll
    for (int s = 0; s < 4; ++s) {
        #pragma unroll
        for (int j = 0; j < 8; ++j) {
            int k = s*32 + kc*8 + j;
            wpk[((size_t)((FR_O1 + s*4 + nt)*64 + l))*8 + j] = f2bf(oW1[k*DD + nt*16 + n0]);
        }
    }
}

// ---------------- histogram + scans ----------------
__global__ __launch_bounds__(256) void k_hist(
    const int* __restrict__ col, u32* __restrict__ cnt, int n_e)
{
    int g = blockIdx.x * 256 + threadIdx.x;
    int base = g * 4;
    if (base + 3 < n_e) {
        int4 c = ((const int4*)col)[g];
        atomicAdd(&cnt[c.x], 1u);
        atomicAdd(&cnt[c.y], 1u);
        atomicAdd(&cnt[c.z], 1u);
        atomicAdd(&cnt[c.w], 1u);
    } else {
        for (int e = base; e < n_e; ++e) atomicAdd(&cnt[col[e]], 1u);
    }
}

__global__ __launch_bounds__(256) void k_scan1(
    const u32* __restrict__ cnt, u32* __restrict__ bsum, int n)
{
    __shared__ u32 s[256];
    int i = blockIdx.x * 256 + threadIdx.x;
    s[threadIdx.x] = (i < n) ? cnt[i] : 0u;
    __syncthreads();
    for (int o = 128; o > 0; o >>= 1) {
        if (threadIdx.x < o) s[threadIdx.x] += s[threadIdx.x + o];
        __syncthreads();
    }
    if (threadIdx.x == 0) bsum[blockIdx.x] = s[0];
}

__global__ __launch_bounds__(512) void k_scan2(
    const u32* __restrict__ bsum, u32* __restrict__ boff, int nb)
{
    __shared__ u32 s[512];
    int t = threadIdx.x;
    u32 v = (t < nb) ? bsum[t] : 0u;
    s[t] = v;
    __syncthreads();
    for (int o = 1; o < 512; o <<= 1) {
        u32 a = (t >= o) ? s[t - o] : 0u;
        __syncthreads();
        s[t] += a;
        __syncthreads();
    }
    if (t < nb) boff[t] = s[t] - v;
}

__global__ __launch_bounds__(256) void k_scan3(
    const u32* __restrict__ cnt, const u32* __restrict__ boff,
    u32* __restrict__ wp, int n)
{
    __shared__ u32 s[256];
    int t = threadIdx.x;
    int i = blockIdx.x * 256 + t;
    u32 v = (i < n) ? cnt[i] : 0u;
    s[t] = v;
    __syncthreads();
    for (int o = 1; o < 256; o <<= 1) {
        u32 a = (t >= o) ? s[t - o] : 0u;
        __syncthreads();
        s[t] += a;
        __syncthreads();
    }
    if (i < n) wp[i] = boff[blockIdx.x] + s[t] - v;
}

// ---------------- counting-sort scatter: edge -> sorted slot ----------------
__global__ __launch_bounds__(256) void k_scatter(
    const int* __restrict__ row, const int* __restrict__ col,
    u32* __restrict__ wp,
    int* __restrict__ esorted, int* __restrict__ rsorted, int* __restrict__ csorted,
    int n_e)
{
    int e = blockIdx.x * 256 + threadIdx.x;
    if (e >= n_e) return;
    int c = col[e];
    u32 p = atomicAdd(&wp[c], 1u);
    esorted[p] = e;
    rsorted[p] = row[e];
    csorted[p] = c;
}

// ---------------- MFMA node MLP: x (N,64) f32 -> x_tb (N,64) bf16 ----------------
__global__ __launch_bounds__(256, 2) void k_node_mfma(
    const float* __restrict__ x,
    const unsigned short* __restrict__ wpk,
    const float* __restrict__ b1, const float* __restrict__ b2,
    unsigned short* __restrict__ x_tb, int n)
{
    __shared__ __align__(16) unsigned short tile[4][16*PADH];
    const int tid  = threadIdx.x;
    const int wv   = tid >> 6;
    const int lane = tid & 63;
    const int kc   = lane >> 4;
    const int n0   = lane & 15;
    const int rbase = kc * 4;

    const short8* fb = (const short8*)wpk;
    short8 bw1[2][4], bw2[2][4];
    #pragma unroll
    for (int s = 0; s < 2; ++s)
        #pragma unroll
        for (int nt = 0; nt < 4; ++nt) {
            bw1[s][nt] = fb[(FR_N1 + s*4 + nt)*64 + lane];
            bw2[s][nt] = fb[(FR_N2 + s*4 + nt)*64 + lane];
        }
    float b1v[4], b2v[4];
    #pragma unroll
    for (int nt = 0; nt < 4; ++nt) { b1v[nt] = b1[nt*16 + n0]; b2v[nt] = b2[nt*16 + n0]; }

    const int base = blockIdx.x*64 + wv*16;
    int rc = min(base + n0, n - 1);
    const float* xr = x + (size_t)rc * DD;

    short8 a[2];
    #pragma unroll
    for (int m = 0; m < 2; ++m) {
        float4 u0 = *(const float4*)(xr + m*32 + kc*8);
        float4 u1 = *(const float4*)(xr + m*32 + kc*8 + 4);
        unsigned* au = (unsigned*)&a[m];
        au[0] = cvt_pk_bf16(u0.x, u0.y);
        au[1] = cvt_pk_bf16(u0.z, u0.w);
        au[2] = cvt_pk_bf16(u1.x, u1.y);
        au[3] = cvt_pk_bf16(u1.z, u1.w);
    }

    f32x4 zz = {0.f, 0.f, 0.f, 0.f};
    f32x4 hacc[4] = {zz, zz, zz, zz};
    #pragma unroll
    for (int m = 0; m < 2; ++m)
        #pragma unroll
        for (int nt = 0; nt < 4; ++nt)
            hacc[nt] = __builtin_amdgcn_mfma_f32_16x16x32_bf16(a[m], bw1[m][nt], hacc[nt], 0, 0, 0);

    #pragma unroll
    for (int nt = 0; nt < 4; ++nt)
        #pragma unroll
        for (int r = 0; r < 4; ++r)
            tile[wv][(rbase + r)*PADH + nt*16 + n0] = f2bf(silu(hacc[nt][r] + b1v[nt]));
    __syncthreads();

    short8 a2_0 = *(const short8*)&tile[wv][n0*PADH +  0 + kc*8];
    short8 a2_1 = *(const short8*)&tile[wv][n0*PADH + 32 + kc*8];
    f32x4 oacc[4];
    #pragma unroll
    for (int nt = 0; nt < 4; ++nt) {
        oacc[nt] = __builtin_amdgcn_mfma_f32_16x16x32_bf16(a2_0, bw2[0][nt], zz, 0, 0, 0);
        oacc[nt] = __builtin_amdgcn_mfma_f32_16x16x32_bf16(a2_1, bw2[1][nt], oacc[nt], 0, 0, 0);
    }
    __syncthreads();

    #pragma unroll
    for (int nt = 0; nt < 4; ++nt)
        #pragma unroll
        for (int r = 0; r < 4; ++r)
            tile[wv][(rbase + r)*PADH + nt*16 + n0] = f2bf(oacc[nt][r] + b2v[nt]);
    __syncthreads();

    int ei = lane >> 2, q = lane & 3;
    int er = base + ei;
    if (er < n) {
        uint4* dst = (uint4*)(x_tb + (size_t)er * DD);
        dst[q]     = *(const uint4*)&tile[wv][ei*PADH + q*8];
        dst[q + 4] = *(const uint4*)&tile[wv][ei*PADH + (q + 4)*8];
    }
}

// ---------------- fused edge kernel: sorted order, segmented reduce into agg ----
// 256 threads = 4 waves; each wave owns 64 consecutive sorted-edge slots
// processed as 4 sub-tiles of 16 edges.
__global__ __launch_bounds__(256) void k_edge_fused(
    const float* __restrict__ pos,
    const float* __restrict__ edge_attr,
    const int* __restrict__ esorted, const int* __restrict__ rsorted,
    const int* __restrict__ csorted,
    const unsigned short* __restrict__ x_tb,
    const unsigned short* __restrict__ wpk,
    const float* __restrict__ b1, const float* __restrict__ b2,
    float* __restrict__ agg, int n_e)
{
    __shared__ __align__(16) unsigned short hid_s[4][16*PADH];
    __shared__ __align__(16) float          msg_s[4][16*PADF];
    __shared__ __align__(16) unsigned short xls[4][16*DD];
    __shared__ int col_s[4][64];

    const int tid  = threadIdx.x;
    const int wv   = tid >> 6;
    const int lane = tid & 63;
    const int kc   = lane >> 4;
    const int n0   = lane & 15;
    const int rb   = kc * 4;

    const short8* fb = (const short8*)wpk;
    short8 bw1[4], bw2[2][4];
    #pragma unroll
    for (int nt = 0; nt < 4; ++nt) bw1[nt] = fb[(FR_E1 + nt)*64 + lane];
    #pragma unroll
    for (int s = 0; s < 2; ++s)
        #pragma unroll
        for (int nt = 0; nt < 4; ++nt) bw2[s][nt] = fb[(FR_E2 + s*4 + nt)*64 + lane];

    float b1v[4], b2v[4];
    #pragma unroll
    for (int nt = 0; nt < 4; ++nt) { b1v[nt] = b1[nt*16 + n0]; b2v[nt] = b2[nt*16 + n0]; }

    const int gbase = blockIdx.x*256 + wv*64;   // this wave's sorted-slot base
    int g  = gbase + lane;
    int gc = min(g, n_e - 1);
    int eo = esorted[gc];
    int rw = rsorted[gc];
    int cl = csorted[gc];
    col_s[wv][lane] = cl;

    // ---- geometry + SH: once per edge (this lane) ----
    float ax = pos[3*rw+0] - pos[3*cl+0];
    float ay = pos[3*rw+1] - pos[3*cl+1];
    float az = pos[3*rw+2] - pos[3*cl+2];
    float len = sqrtf(fmaf(ax,ax, fmaf(ay,ay, az*az)) + 1e-12f);
    float dx = ax/len, dy = ay/len, dz = az/len;
    float n2 = sqrtf(fmaf(dx,dx, fmaf(dy,dy, dz*dz)));
    float inv = 1.0f/(n2 + 1e-10f);
    dx *= inv; dy *= inv; dz *= inv;

    float sh[9];
    sh[0] = 0.28209479177387814f;
    sh[1] = 0.4886025119029199f*dy;
    sh[2] = 0.4886025119029199f*dz;
    sh[3] = 0.4886025119029199f*dx;
    sh[4] = 1.0925484305920792f*dx*dy;
    sh[5] = 1.0925484305920792f*dy*dz;
    sh[6] = 0.31539156525252005f*(3.0f*dz*dz - 1.0f);
    sh[7] = 1.0925484305920792f*dx*dz;
    sh[8] = 0.5462742152960396f*(dx*dx - dy*dy);

    f32x4 zz = {0.f, 0.f, 0.f, 0.f};

    #pragma unroll 1
    for (int t = 0; t < 4; ++t) {
        // ---- stage x_tb rows of this sub-tile's 16 edges (4 lanes/row, 32B each)
        {
            int lr = t*16 + (lane >> 2);            // local edge idx
            int rv = __shfl(rw, lr);
            int ch = lane & 3;
            const uint4* src = (const uint4*)(x_tb + (size_t)rv * DD);
            uint4 v0 = src[ch*2], v1 = src[ch*2 + 1];
            uint4* d = (uint4*)&xls[wv][(lr - t*16)*DD];
            d[ch*2]     = v0;
            d[ch*2 + 1] = v1;
        }

        // ---- A-fragment: SH via shfl broadcast, attr via coalesced loads
        int le = t*16 + n0;                          // local edge for this lane's frag column
        float shv[8], sh8;
        #pragma unroll
        for (int j = 0; j < 8; ++j) shv[j] = __shfl(sh[j], le);
        sh8 = __shfl(sh[8], le);

        float fv[8];
        #pragma unroll
        for (int j = 0; j < 8; ++j) fv[j] = 0.0f;
        if (kc < 2) {
            int ea = __shfl(eo, le);
            const float4* ap = (const float4*)(edge_attr + (size_t)ea*EDA + kc*8);
            float4 a0 = ap[0], a1 = ap[1];
            fv[0]=a0.x; fv[1]=a0.y; fv[2]=a0.z; fv[3]=a0.w;
            fv[4]=a1.x; fv[5]=a1.y; fv[6]=a1.z; fv[7]=a1.w;
        } else if (kc == 2) {
            #pragma unroll
            for (int j = 0; j < 8; ++j) fv[j] = shv[j];
        } else {
            fv[0] = sh8;
        }

        short8 af;
        {
            unsigned* au = (unsigned*)&af;
            au[0] = cvt_pk_bf16(fv[0], fv[1]);
            au[1] = cvt_pk_bf16(fv[2], fv[3]);
            au[2] = cvt_pk_bf16(fv[4], fv[5]);
            au[3] = cvt_pk_bf16(fv[6], fv[7]);
        }

        // ---- GEMM1 + silu -> hid_s (bf16)
        f32x4 hacc[4];
        #pragma unroll
        for (int nt = 0; nt < 4; ++nt)
            hacc[nt] = __builtin_amdgcn_mfma_f32_16x16x32_bf16(af, bw1[nt], zz, 0, 0, 0);

        #pragma unroll
        for (int nt = 0; nt < 4; ++nt)
            #pragma unroll
            for (int r = 0; r < 4; ++r)
                hid_s[wv][(rb + r)*PADH + nt*16 + n0] = f2bf(silu(hacc[nt][r] + b1v[nt]));
        __syncthreads();

        // ---- GEMM2
        short8 a2_0 = *(const short8*)&hid_s[wv][n0*PADH +  0 + kc*8];
        short8 a2_1 = *(const short8*)&hid_s[wv][n0*PADH + 32 + kc*8];
        f32x4 oacc[4];
        #pragma unroll
        for (int nt = 0; nt < 4; ++nt) {
            oacc[nt] = __builtin_amdgcn_mfma_f32_16x16x32_bf16(a2_0, bw2[0][nt], zz, 0, 0, 0);
            oacc[nt] = __builtin_amdgcn_mfma_f32_16x16x32_bf16(a2_1, bw2[1][nt], oacc[nt], 0, 0, 0);
        }

        // ---- epilogue: msg (f32, in LDS) = (out + b2) * x_t[row]; zero invalid rows
        #pragma unroll
        for (int r = 0; r < 4; ++r) {
            int lrow = rb + r;
            bool rv2 = (gbase + t*16 + lrow) < n_e;
            #pragma unroll
            for (int nt = 0; nt < 4; ++nt) {
                float xv = bf2f(xls[wv][lrow*DD + nt*16 + n0]);
                float m  = (oacc[nt][r] + b2v[nt]) * xv;
                msg_s[wv][lrow*PADF + nt*16 + n0] = rv2 ? m : 0.0f;
            }
        }
        __syncthreads();

        // ---- segmented reduce over the 16 sorted rows; lane = feature
        {
            const int* cs = &col_s[wv][t*16];
            float acc = 0.0f;
            #pragma unroll
            for (int r = 0; r < 16; ++r) {
                acc += msg_s[wv][r*PADF + lane];
                int cur = cs[r];
                bool flush = (r == 15) || (cs[r+1] != cur);
                if (flush) {
                    unsafeAtomicAdd(&agg[(size_t)cur*DD + lane], acc);
                    acc = 0.0f;
                }
            }
        }
        __syncthreads();
    }
}

// ---------------- MFMA out MLP (+ /cnt) + fused BN partial sums ----------------
__global__ __launch_bounds__(256, 2) void k_out_mfma(
    const float* __restrict__ agg, const u32* __restrict__ cnt,
    const float* __restrict__ x,
    const unsigned short* __restrict__ wpk,
    const float* __restrict__ b1, const float* __restrict__ b2,
    float* __restrict__ h, float* __restrict__ sums, int n)
{
    __shared__ __align__(16) unsigned short htile[4][16*PADH];
    __shared__ __align__(16) float otile[4][16*PADF];
    const int tid  = threadIdx.x;
    const int wv   = tid >> 6;
    const int lane = tid & 63;
    const int kc   = lane >> 4;
    const int n0   = lane & 15;
    const int rbase = kc * 4;

    const short8* fb = (const short8*)wpk;
    short8 bw1[4][4], bw2[2][4];
    #pragma unroll
    for (int s = 0; s < 4; ++s)
        #pragma unroll
        for (int nt = 0; nt < 4; ++nt) bw1[s][nt] = fb[(FR_O1 + s*4 + nt)*64 + lane];
    #pragma unroll
    for (int s = 0; s < 2; ++s)
        #pragma unroll
        for (int nt = 0; nt < 4; ++nt) bw2[s][nt] = fb[(FR_O2 + s*4 + nt)*64 + lane];

    float b1v[4], b2v[4];
    #pragma unroll
    for (int nt = 0; nt < 4; ++nt) { b1v[nt] = b1[nt*16 + n0]; b2v[nt] = b2[nt*16 + n0]; }

    const int base = blockIdx.x*64 + wv*16;
    int rc = min(base + n0, n - 1);
    const float* ar = agg + (size_t)rc * DD;
    const float* xr = x   + (size_t)rc * DD;
    float invc = 1.0f / fmaxf((float)cnt[rc], 1.0f);

    short8 a[4];
    #pragma unroll
    for (int m = 0; m < 4; ++m) {
        const float* src = (m < 2) ? (ar + m*32 + kc*8) : (xr + (m-2)*32 + kc*8);
        float4 u0 = *(const float4*)(src);
        float4 u1 = *(const float4*)(src + 4);
        if (m < 2) {
            u0.x*=invc; u0.y*=invc; u0.z*=invc; u0.w*=invc;
            u1.x*=invc; u1.y*=invc; u1.z*=invc; u1.w*=invc;
        }
        unsigned* au = (unsigned*)&a[m];
        au[0] = cvt_pk_bf16(u0.x, u0.y);
        au[1] = cvt_pk_bf16(u0.z, u0.w);
        au[2] = cvt_pk_bf16(u1.x, u1.y);
        au[3] = cvt_pk_bf16(u1.z, u1.w);
    }

    f32x4 zz = {0.f, 0.f, 0.f, 0.f};
    f32x4 hacc[4] = {zz, zz, zz, zz};
    #pragma unroll
    for (int m = 0; m < 4; ++m)
        #pragma unroll
        for (int nt = 0; nt < 4; ++nt)
            hacc[nt] = __builtin_amdgcn_mfma_f32_16x16x32_bf16(a[m], bw1[m][nt], hacc[nt], 0, 0, 0);

    #pragma unroll
    for (int nt = 0; nt < 4; ++nt)
        #pragma unroll
        for (int r = 0; r < 4; ++r)
            htile[wv][(rbase + r)*PADH + nt*16 + n0] = f2bf(silu(hacc[nt][r] + b1v[nt]));
    __syncthreads();

    short8 a2_0 = *(const short8*)&htile[wv][n0*PADH +  0 + kc*8];
    short8 a2_1 = *(const short8*)&htile[wv][n0*PADH + 32 + kc*8];
    f32x4 oacc[4];
    #pragma unroll
    for (int nt = 0; nt < 4; ++nt) {
        oacc[nt] = __builtin_amdgcn_mfma_f32_16x16x32_bf16(a2_0, bw2[0][nt], zz, 0, 0, 0);
        oacc[nt] = __builtin_amdgcn_mfma_f32_16x16x32_bf16(a2_1, bw2[1][nt], oacc[nt], 0, 0, 0);
    }

    #pragma unroll
    for (int nt = 0; nt < 4; ++nt)
        #pragma unroll
        for (int r = 0; r < 4; ++r)
            otile[wv][(rbase + r)*PADF + nt*16 + n0] = oacc[nt][r] + b2v[nt];
    __syncthreads();

    int ei = lane >> 2, q = lane & 3;
    int er = base + ei;
    if (er < n) {
        float4* dst = (float4*)(h + (size_t)er * DD);
        #pragma unroll
        for (int k = 0; k < 4; ++k)
            dst[q + 4*k] = *(const float4*)&otile[wv][ei*PADF + (q + 4*k)*4];
    }

    if (tid < 64) {
        int f = tid;
        float s = 0.f, qq = 0.f;
        #pragma unroll
        for (int w = 0; w < 4; ++w) {
            int base_w = blockIdx.x*64 + w*16;
            int nv = n - base_w;
            nv = nv < 0 ? 0 : (nv > 16 ? 16 : nv);
            for (int r = 0; r < nv; ++r) {
                float v = otile[w][r*PADF + f];
                s += v; qq = fmaf(v, v, qq);
            }
        }
        unsafeAtomicAdd(&sums[f], s);
        unsafeAtomicAdd(&sums[DD + f], qq);
    }
}

// ---------------- BN finalize + normalize ----------------
__global__ void k_bn_finalize(const float* __restrict__ sums,
                              const float* __restrict__ gamma, const float* __restrict__ beta,
                              float* __restrict__ ss, float inv_n)
{
    int j = threadIdx.x;   // 64 threads
    float m = sums[j] * inv_n;
    float var = sums[DD+j] * inv_n - m*m;
    float sc = gamma[j] * rsqrtf(var + 1e-5f);
    ss[j] = sc;
    ss[DD+j] = beta[j] - m*sc;
}

__global__ __launch_bounds__(256) void k_bn_norm(
    float* __restrict__ h, const float* __restrict__ ss, int total4)
{
    int g = blockIdx.x*256 + threadIdx.x;
    if (g >= total4) return;
    int f0 = (g*4) & (DD-1);
    float4 v = ((const float4*)h)[g];
    v.x = fmaf(v.x, ss[f0+0], ss[DD+f0+0]);
    v.y = fmaf(v.y, ss[f0+1], ss[DD+f0+1]);
    v.z = fmaf(v.z, ss[f0+2], ss[DD+f0+2]);
    v.w = fmaf(v.w, ss[f0+3], ss[DD+f0+3]);
    ((float4*)h)[g] = v;
}

static inline size_t al16(size_t v) { return (v + 15) & ~(size_t)15; }

extern "C" void kernel_launch(void* const* d_in, const int* in_sizes, int n_in,
                              void* d_out, int out_size, void* d_ws, size_t ws_size,
                              hipStream_t stream)
{
    const float* x         = (const float*)d_in[0];
    const float* pos       = (const float*)d_in[1];
    const float* edge_attr = (const float*)d_in[2];
    const int*   row       = (const int*)d_in[3];
    const int*   col       = (const int*)d_in[4];
    const float* nW1 = (const float*)d_in[5];
    const float* nb1 = (const float*)d_in[6];
    const float* nW2 = (const float*)d_in[7];
    const float* nb2 = (const float*)d_in[8];
    const float* eW1 = (const float*)d_in[9];
    const float* eb1 = (const float*)d_in[10];
    const float* eW2 = (const float*)d_in[11];
    const float* eb2 = (const float*)d_in[12];
    const float* oW1 = (const float*)d_in[13];
    const float* ob1 = (const float*)d_in[14];
    const float* oW2 = (const float*)d_in[15];
    const float* ob2 = (const float*)d_in[16];
    const float* gamma = (const float*)d_in[17];
    const float* beta  = (const float*)d_in[18];

    const int N = in_sizes[0] / DD;   // 100000
    const int E = in_sizes[3];        // 1600000
    const int NB = (N + 255) / 256;   // 391

    float* hout = (float*)d_out;
    char* ws = (char*)d_ws;

    // layout: [x_tb][cnt][sums][agg]  <- cnt..agg memset in one shot
    size_t o_xtb  = 0;
    size_t o_cnt  = o_xtb  + (size_t)N*DD*2;
    size_t o_sums = o_cnt  + (size_t)N*4;
    size_t o_agg  = o_sums + 128*4;
    size_t o_ss   = o_agg  + (size_t)N*DD*4;
    size_t o_wp   = o_ss   + 128*4;
    size_t o_bsum = o_wp   + (size_t)N*4;
    size_t o_boff = al16(o_bsum + (size_t)NB*4);
    size_t o_wpk  = al16(o_boff + (size_t)NB*4);
    size_t o_eso  = al16(o_wpk + (size_t)FR_TOT*64*8*2);
    size_t o_rso  = o_eso + (size_t)E*4;
    size_t o_cso  = o_rso + (size_t)E*4;
    size_t need   = o_cso + (size_t)E*4;

    if (ws_size < need) return;

    unsigned short* x_tb = (unsigned short*)(ws + o_xtb);
    u32*   cnt  = (u32*)(ws + o_cnt);
    float* sums = (float*)(ws + o_sums);
    float* agg  = (float*)(ws + o_agg);
    float* ssb  = (float*)(ws + o_ss);
    u32*   wp   = (u32*)(ws + o_wp);
    u32*   bsum = (u32*)(ws + o_bsum);
    u32*   boff = (u32*)(ws + o_boff);
    unsigned short* wpk = (unsigned short*)(ws + o_wpk);
    int* esorted = (int*)(ws + o_eso);
    int* rsorted = (int*)(ws + o_rso);
    int* csorted = (int*)(ws + o_cso);

    // zero cnt + sums + agg (contiguous)
    hipMemsetAsync(cnt, 0, (size_t)N*4 + 128*4 + (size_t)N*DD*4, stream);

    k_pack_w<<<1, 256, 0, stream>>>(eW1, eW2, nW1, nW2, oW1, oW2, wpk);
    k_hist <<<(E/4 + 255)/256, 256, 0, stream>>>(col, cnt, E);
    k_scan1<<<NB, 256, 0, stream>>>(cnt, bsum, N);
    k_scan2<<<1, 512, 0, stream>>>(bsum, boff, NB);
    k_scan3<<<NB, 256, 0, stream>>>(cnt, boff, wp, N);
    k_scatter<<<(E + 255)/256, 256, 0, stream>>>(row, col, wp, esorted, rsorted, csorted, E);
    k_node_mfma<<<(N + 63)/64, 256, 0, stream>>>(x, wpk, nb1, nb2, x_tb, N);
    k_edge_fused<<<(E + 255)/256, 256, 0, stream>>>(pos, edge_attr, esorted, rsorted, csorted,
                                                    x_tb, wpk, eb1, eb2, agg, E);
    k_out_mfma<<<(N + 63)/64, 256, 0, stream>>>(agg, cnt, x, wpk, ob1, ob2, hout, sums, N);
    k_bn_finalize<<<1, 64, 0, stream>>>(sums, gamma, beta, ssb, 1.0f/(float)N);
    k_bn_norm<<<(N*DD/4 + 255)/256, 256, 0, stream>>>(hout, ssb, N*DD/4);
}